// Round 2
// 282.888 us; speedup vs baseline: 1.0581x; 1.0581x over previous
//
#include <hip/hip_runtime.h>

typedef __bf16 bf16;
typedef __bf16 bf16x4 __attribute__((ext_vector_type(4)));
typedef __bf16 bf16x8 __attribute__((ext_vector_type(8)));
typedef float  f32x4  __attribute__((ext_vector_type(4)));
typedef float  f32x16 __attribute__((ext_vector_type(16)));
typedef unsigned u32x4 __attribute__((ext_vector_type(4)));

#define NH   16
#define HD   64
#define DQ   1024
#define DKV  768
#define LQ   4096
#define LKV  1024
#define NB   2

__device__ __forceinline__ f32x4 mfma16(bf16x8 a, bf16x8 b, f32x4 c) {
    return __builtin_amdgcn_mfma_f32_16x16x32_bf16(a, b, c, 0, 0, 0);
}
__device__ __forceinline__ f32x16 mfma32(bf16x8 a, bf16x8 b, f32x16 c) {
    return __builtin_amdgcn_mfma_f32_32x32x16_bf16(a, b, c, 0, 0, 0);
}

// exchange a.hi-lanes <-> b.lo-lanes: after call a = (a.lo, b.lo), b = (a.hi, b.hi)
__device__ __forceinline__ void plswap(unsigned &a, unsigned &b) {
#if __has_builtin(__builtin_amdgcn_permlane32_swap)
    auto r = __builtin_amdgcn_permlane32_swap(a, b, false, false);
    a = (unsigned)r[0]; b = (unsigned)r[1];
#else
    asm volatile("v_permlane32_swap_b32 %0, %1" : "+v"(a), "+v"(b));
#endif
}

// async global->LDS, 16B per lane; LDS dest wave-uniform base (HW adds lane*16)
#define GLDS16(g, l) __builtin_amdgcn_global_load_lds(                      \
    (const __attribute__((address_space(1))) void*)(g),                     \
    (__attribute__((address_space(3))) void*)(l), 16, 0, 0)

// ------- prep: 4 weight transposes (f32 KxN -> bf16 NxK) + x/y f32->bf16 -----
__global__ __launch_bounds__(256) void prep(
        const float* __restrict__ Wq, const float* __restrict__ Wk,
        const float* __restrict__ Wv, const float* __restrict__ Wo,
        bf16* __restrict__ Wq_t, bf16* __restrict__ Wk_t,
        bf16* __restrict__ Wv_t, bf16* __restrict__ Wo_t,
        const float* __restrict__ x, const float* __restrict__ y,
        bf16* __restrict__ xb, bf16* __restrict__ yb,
        int nx8, int ntot8) {
    if (blockIdx.z < 4) {
        __shared__ float tile[32][33];
        const float* in; bf16* out; int K;
        switch (blockIdx.z) {
            case 0:  in = Wq; out = Wq_t; K = DQ;  break;
            case 1:  in = Wk; out = Wk_t; K = DKV; break;
            case 2:  in = Wv; out = Wv_t; K = DKV; break;
            default: in = Wo; out = Wo_t; K = DQ;  break;
        }
        int n0 = blockIdx.x * 32, k0 = blockIdx.y * 32;
        if (k0 >= K) return;
        int tx = threadIdx.x, ty = threadIdx.y;  // (32,8)
        for (int yy = 0; yy < 32; yy += 8)
            tile[ty + yy][tx] = in[(size_t)(k0 + ty + yy) * DQ + n0 + tx];
        __syncthreads();
        for (int yy = 0; yy < 32; yy += 8)
            out[(size_t)(n0 + ty + yy) * K + k0 + tx] = (bf16)tile[tx][ty + yy];
    } else {
        int tid = threadIdx.y * 32 + threadIdx.x;
        int flat = (blockIdx.y * 32 + blockIdx.x) * 256 + tid;  // 0..262143
        for (int i = flat; i < ntot8; i += 32 * 32 * 256) {
            const float* in; bf16* out; int j;
            if (i < nx8) { in = x; out = xb; j = i; }
            else         { in = y; out = yb; j = i - nx8; }
            float4 a0 = ((const float4*)in)[(size_t)j * 2];
            float4 a1 = ((const float4*)in)[(size_t)j * 2 + 1];
            bf16x8 v = {(bf16)a0.x, (bf16)a0.y, (bf16)a0.z, (bf16)a0.w,
                        (bf16)a1.x, (bf16)a1.y, (bf16)a1.z, (bf16)a1.w};
            ((bf16x8*)out)[j] = v;
        }
    }
}

// ------- 128x128-tile GEMM body: C = A(MxK,bf16) @ Bt(NxK,bf16)^T + bias -----
// MODE 0: C bf16 row-major. MODE 1: V-transposed bf16 vT[b,h,d,kv]. MODE 2: C f32.
template <int MODE>
__device__ __forceinline__ void gemm_body(const bf16* __restrict__ A,
                                          const bf16* __restrict__ Bt,
                                          const float* __restrict__ bias,
                                          void* __restrict__ Cv,
                                          int N, int K, int m0) {
    __shared__ bf16 As[128 * 32];
    __shared__ bf16 Bs[128 * 32];
    int tid  = threadIdx.x;
    int lane = tid & 63, w = tid >> 6;
    int quad = lane >> 4, l15 = lane & 15;
    int wm = (w >> 1) * 64, wn = (w & 1) * 64;
    int n0 = blockIdx.x * 128;
    int srow = tid >> 2, scol = (tid & 3) * 8;
    const bf16* Ag = &A [(size_t)(m0 + srow) * K + scol];
    const bf16* Bg = &Bt[(size_t)(n0 + srow) * K + scol];
    bf16* Asw = As + w * 512;
    bf16* Bsw = Bs + w * 512;

    f32x4 acc[4][4] = {};

    for (int k0 = 0; k0 < K; k0 += 32) {
        GLDS16(Ag + k0,                  Asw);
        GLDS16(Ag + (size_t)64 * K + k0, Asw + 2048);
        GLDS16(Bg + k0,                  Bsw);
        GLDS16(Bg + (size_t)64 * K + k0, Bsw + 2048);
        __syncthreads();
        bf16x8 af[4], bfr[4];
#pragma unroll
        for (int i = 0; i < 4; i++)
            af[i] = *(const bf16x8*)&As[(size_t)(wm + i * 16 + l15) * 32 + quad * 8];
#pragma unroll
        for (int j = 0; j < 4; j++)
            bfr[j] = *(const bf16x8*)&Bs[(size_t)(wn + j * 16 + l15) * 32 + quad * 8];
#pragma unroll
        for (int i = 0; i < 4; i++)
#pragma unroll
            for (int j = 0; j < 4; j++)
                acc[i][j] = mfma16(af[i], bfr[j], acc[i][j]);
        __syncthreads();
    }

    bf16*  Cb = (bf16*)Cv;
    float* Cf = (float*)Cv;
#pragma unroll
    for (int i = 0; i < 4; i++)
#pragma unroll
        for (int j = 0; j < 4; j++) {
            int col = n0 + wn + j * 16 + l15;
            float bcol = bias[col];
            if (MODE == 1) {
                int rowb = m0 + wm + i * 16 + quad * 4;      // 4 consecutive kv
                int bb = rowb >> 10, kv = rowb & 1023;       // LKV = 1024
                int h = col >> 6, d = col & 63;
                bf16x4 val = {(bf16)(acc[i][j][0] + bcol), (bf16)(acc[i][j][1] + bcol),
                              (bf16)(acc[i][j][2] + bcol), (bf16)(acc[i][j][3] + bcol)};
                *(bf16x4*)&Cb[(((size_t)(bb * NH + h) * HD) + d) * LKV + kv] = val;
            } else {
#pragma unroll
                for (int r = 0; r < 4; r++) {
                    int row = m0 + wm + i * 16 + quad * 4 + r;
                    float v = acc[i][j][r] + bcol;
                    if (MODE == 2) Cf[(size_t)row * N + col] = v;
                    else           Cb[(size_t)row * N + col] = (bf16)v;
                }
            }
        }
}

// one launch: y<64 -> Q-proj tiles, 64..79 -> K-proj, 80..95 -> V-proj
__global__ __launch_bounds__(256) void gemm_qkv(
        const bf16* xb, const bf16* Wq_t, const float* bq, bf16* qbuf,
        const bf16* yb, const bf16* Wk_t, const float* bk, bf16* kbuf,
        const bf16* Wv_t, const float* bv, bf16* vT) {
    int y = blockIdx.y;
    if (y < 64)      gemm_body<0>(xb, Wq_t, bq, qbuf, DQ, DQ,  y * 128);
    else if (y < 80) gemm_body<0>(yb, Wk_t, bk, kbuf, DQ, DKV, (y - 64) * 128);
    else             gemm_body<1>(yb, Wv_t, bv, vT,   DQ, DKV, (y - 80) * 128);
}
__global__ __launch_bounds__(256) void gemm_o(const bf16* A, const bf16* Bt,
                                              const float* bias, void* Cv) {
    gemm_body<2>(A, Bt, bias, Cv, DQ, DQ, blockIdx.y * 128);
}

// ------- RMSNorm + RoPE, one wave per row, register-resident -----------------
__global__ __launch_bounds__(256) void rmsnorm_rope3(bf16* __restrict__ qb,
                                                     bf16* __restrict__ kb,
                                                     const float* __restrict__ gq,
                                                     const float* __restrict__ gk,
                                                     const float* __restrict__ xc,
                                                     const float* __restrict__ xs,
                                                     const float* __restrict__ yc,
                                                     const float* __restrict__ ys) {
    int w = threadIdx.x >> 6, lane = threadIdx.x & 63;
    int row = blockIdx.x * 4 + w;
    bf16* t; const float *g, *cs, *sn;
    if (row < NB * LQ) {
        t = qb + (size_t)row * DQ; g = gq;
        cs = xc + (size_t)row * HD; sn = xs + (size_t)row * HD;
    } else {
        int r2 = row - NB * LQ;
        t = kb + (size_t)r2 * DQ; g = gk;
        cs = yc + (size_t)r2 * HD; sn = ys + (size_t)r2 * HD;
    }
    int c0 = lane * 16;
    bf16x8 a0 = *(const bf16x8*)&t[c0];
    bf16x8 a1 = *(const bf16x8*)&t[c0 + 8];
    float vv[16], ss = 0.f;
#pragma unroll
    for (int j = 0; j < 8; j++) { vv[j] = (float)a0[j]; vv[8 + j] = (float)a1[j]; }
#pragma unroll
    for (int j = 0; j < 16; j++) ss += vv[j] * vv[j];
#pragma unroll
    for (int off = 32; off >= 1; off >>= 1) ss += __shfl_xor(ss, off, 64);
    float rms = rsqrtf(ss * (1.0f / 1024.0f) + 1e-6f);
    float nv[16];
#pragma unroll
    for (int j = 0; j < 16; j++) nv[j] = vv[j] * rms * g[c0 + j];
    int d0 = (lane & 3) * 16;
    float sgn = (lane & 2) ? 1.f : -1.f;   // d<32 -> -partner, d>=32 -> +partner
    bf16x8 o0, o1;
#pragma unroll
    for (int j = 0; j < 16; j++) {
        float pv = __shfl_xor(nv[j], 2, 64);
        float r = nv[j] * cs[d0 + j] + sgn * pv * sn[d0 + j];
        if (j < 8) o0[j] = (bf16)r; else o1[j - 8] = (bf16)r;
    }
    *(bf16x8*)&t[c0]     = o0;
    *(bf16x8*)&t[c0 + 8] = o1;
}

// ------- flash attention v6: 32x32 MFMA, in-register P, GLDS16 staging -------
// block = (b,h,128 q rows); wave w owns q rows w*32..w*32+31 (q = l31, both
// hi-halves of the wave hold the same q, disjoint kv/d quarters).
// K/V chunk (64 kv) double-buffered in UNPADDED [64][64] LDS staged by
// global_load_lds with XOR-swizzled per-lane SOURCE addresses (rule #21):
// LDS slot p of row r holds logical 16B-slot p^(r&7); reads XOR the same
// pattern -> conflict-free ds_read_b128 on 32-row column slices.
// P never touches LDS: 32x32 C-layout keeps a full P row per lane; the
// B-operand fragment is built with v_cvt_pk_bf16_f32 + permlane32_swap (T12).
__global__ __launch_bounds__(256, 4) void attn_kern(const bf16* __restrict__ q,
                                                    const bf16* __restrict__ k,
                                                    const bf16* __restrict__ vT,
                                                    bf16* __restrict__ o) {
    __shared__ bf16 Ks[2][64][64];          // [buf][kv][d]   (swizzled slots)
    __shared__ bf16 Vs[2][64][64];          // [buf][d][kv]   (swizzled slots)
    int tid = threadIdx.x, w = tid >> 6, lane = tid & 63;
    int l31 = lane & 31, hi = lane >> 5;
    int b = blockIdx.z, h = blockIdx.y, qt = blockIdx.x;
    int qrow = qt * 128 + w * 32 + l31;
    int sw8 = (l31 & 7) << 3;               // read-side element XOR (16B granular)

    // Q fragments (B-operand): col=q=l31, k(d) = kc*16 + hi*8 + e; fold 1/8 scale
    bf16x8 qf[4];
    {
        const bf16* qg = &q[((size_t)(b * LQ) + qrow) * DQ + h * HD + hi * 8];
#pragma unroll
        for (int kc = 0; kc < 4; kc++) {
            bf16x8 tq = *(const bf16x8*)(qg + kc * 16);
#pragma unroll
            for (int e = 0; e < 8; e++) tq[e] = (bf16)((float)tq[e] * 0.125f);
            qf[kc] = tq;
        }
    }

    // staging: wave w stages rows [w*16, w*16+16) of K (kv rows) and V (d rows).
    // each GLDS16 covers 8 rows: lane -> row rb+(lane>>3), dest slot lane&7;
    // source slot = (lane&7) ^ (row&7)  (inverse swizzle; (row+8)&7 == row&7)
    int rb = w * 16;
    int srow = rb + (lane >> 3);
    int sl = (lane & 7) ^ (srow & 7);
    const bf16* kg0 = &k[((size_t)(b * LKV) + srow) * DQ + h * HD + sl * 8];
    const bf16* vg0 = &vT[(((size_t)(b * NH + h) * HD) + srow) * LKV + sl * 8];

    GLDS16(kg0,                   &Ks[0][rb][0]);
    GLDS16(kg0 + (size_t)8 * DQ,  &Ks[0][rb + 8][0]);
    GLDS16(vg0,                   &Vs[0][rb][0]);
    GLDS16(vg0 + (size_t)8 * LKV, &Vs[0][rb + 8][0]);
    __syncthreads();

    f32x16 O0 = {}, O1 = {};
    float m_run = -1e30f, l_run = 0.f;

    for (int i = 0; i < 16; i++) {
        int cur = i & 1;
        if (i < 15) {                        // async prefetch of chunk i+1
            int nxt = cur ^ 1;
            size_t ko = (size_t)(i + 1) * 64 * DQ;
            int    vo = (i + 1) * 64;
            GLDS16(kg0 + ko,                   &Ks[nxt][rb][0]);
            GLDS16(kg0 + ko + (size_t)8 * DQ,  &Ks[nxt][rb + 8][0]);
            GLDS16(vg0 + vo,                   &Vs[nxt][rb][0]);
            GLDS16(vg0 + vo + (size_t)8 * LKV, &Vs[nxt][rb + 8][0]);
        }
#pragma unroll
        for (int t = 0; t < 2; t++) {
            // S^T tile (32 kv x 32 q): rows kv = t*32.., cols q = l31
            f32x16 S = {};
            {
                int krow = t * 32 + l31;
                __builtin_amdgcn_s_setprio(1);
#pragma unroll
                for (int kc = 0; kc < 4; kc++) {
                    bf16x8 kf = *(const bf16x8*)&Ks[cur][krow][(kc * 16 + hi * 8) ^ sw8];
                    S = mfma32(kf, qf[kc], S);
                }
                __builtin_amdgcn_s_setprio(0);
            }
            // row max (tree) + cross-half; T13 defer-max rescale
            float m01 = fmaxf(fmaxf(S[0], S[1]),  fmaxf(S[2], S[3]));
            float m23 = fmaxf(fmaxf(S[4], S[5]),  fmaxf(S[6], S[7]));
            float m45 = fmaxf(fmaxf(S[8], S[9]),  fmaxf(S[10], S[11]));
            float m67 = fmaxf(fmaxf(S[12], S[13]), fmaxf(S[14], S[15]));
            float pmax = fmaxf(fmaxf(m01, m23), fmaxf(m45, m67));
            pmax = fmaxf(pmax, __shfl_xor(pmax, 32, 64));
            if (!__all(pmax - m_run <= 8.f)) {
                float mn = fmaxf(m_run, pmax);
                float alpha = __expf(m_run - mn);
                m_run = mn; l_run *= alpha;
#pragma unroll
                for (int r = 0; r < 16; r++) { O0[r] *= alpha; O1[r] *= alpha; }
            }
            float rs = 0.f;
#pragma unroll
            for (int r = 0; r < 16; r++) { S[r] = __expf(S[r] - m_run); rs += S[r]; }
            rs += __shfl_xor(rs, 32, 64);
            l_run += rs;
            // pack P to bf16 pairs: dw[g*2+h] = (p[4g+2h], p[4g+2h+1])
            unsigned dw[8];
#pragma unroll
            for (int g = 0; g < 4; g++)
#pragma unroll
                for (int hh = 0; hh < 2; hh++) {
                    unsigned d_;
                    asm("v_cvt_pk_bf16_f32 %0, %1, %2"
                        : "=v"(d_) : "v"(S[4 * g + 2 * hh]), "v"(S[4 * g + 2 * hh + 1]));
                    dw[g * 2 + hh] = d_;
                }
            // B-fragments for PV: one permlane32_swap pair per K=16 chunk
#pragma unroll
            for (int kcl = 0; kcl < 2; kcl++) {
                int kc = t * 2 + kcl;
                unsigned a0 = dw[(2 * kcl) * 2 + 0], b0 = dw[(2 * kcl + 1) * 2 + 0];
                unsigned a1 = dw[(2 * kcl) * 2 + 1], b1 = dw[(2 * kcl + 1) * 2 + 1];
                plswap(a0, b0);
                plswap(a1, b1);
                u32x4 pw = {a0, a1, b0, b1};
                bf16x8 pb = __builtin_bit_cast(bf16x8, pw);
                int vcol = (kc * 16 + hi * 8) ^ sw8;
                bf16x8 vf0 = *(const bf16x8*)&Vs[cur][l31][vcol];
                bf16x8 vf1 = *(const bf16x8*)&Vs[cur][32 + l31][vcol];
                __builtin_amdgcn_s_setprio(1);
                O0 = mfma32(vf0, pb, O0);
                O1 = mfma32(vf1, pb, O1);
                __builtin_amdgcn_s_setprio(0);
            }
        }
        if (i < 15) __syncthreads();        // drains GLDS16 (vmcnt) + LDS reuse
    }

    float inv = 1.0f / l_run;
    size_t ob = ((size_t)(b * LQ) + qrow) * DQ + h * HD;
#pragma unroll
    for (int td = 0; td < 2; td++) {
        const f32x16& O = td ? O1 : O0;
#pragma unroll
        for (int g = 0; g < 4; g++) {
            bf16x4 ov = {(bf16)(O[4 * g + 0] * inv), (bf16)(O[4 * g + 1] * inv),
                         (bf16)(O[4 * g + 2] * inv), (bf16)(O[4 * g + 3] * inv)};
            *(bf16x4*)&o[ob + td * 32 + g * 8 + hi * 4] = ov;
        }
    }
}

// ---------------------------------------------------------------------------
extern "C" void kernel_launch(void* const* d_in, const int* in_sizes, int n_in,
                              void* d_out, int out_size, void* d_ws, size_t ws_size,
                              hipStream_t stream) {
    const float* x     = (const float*)d_in[0];
    const float* y     = (const float*)d_in[1];
    const float* x_cos = (const float*)d_in[2];
    const float* x_sin = (const float*)d_in[3];
    const float* y_cos = (const float*)d_in[4];
    const float* y_sin = (const float*)d_in[5];
    const float* Wq    = (const float*)d_in[6];
    const float* bq    = (const float*)d_in[7];
    const float* Wk    = (const float*)d_in[8];
    const float* bk    = (const float*)d_in[9];
    const float* Wv    = (const float*)d_in[10];
    const float* bv    = (const float*)d_in[11];
    const float* Wo    = (const float*)d_in[12];
    const float* bo    = (const float*)d_in[13];
    const float* gq    = (const float*)d_in[14];
    const float* gk    = (const float*)d_in[15];

    char* ws = (char*)d_ws;
    bf16* Wq_t = (bf16*)ws;  ws += (size_t)DQ * DQ * 2;
    bf16* Wk_t = (bf16*)ws;  ws += (size_t)DQ * DKV * 2;
    bf16* Wv_t = (bf16*)ws;  ws += (size_t)DQ * DKV * 2;
    bf16* Wo_t = (bf16*)ws;  ws += (size_t)DQ * DQ * 2;
    bf16* qbuf = (bf16*)ws;  ws += (size_t)NB * LQ * DQ * 2;
    bf16* kbuf = (bf16*)ws;  ws += (size_t)NB * LKV * DQ * 2;
    bf16* vT   = (bf16*)ws;  ws += (size_t)NB * NH * HD * LKV * 2;
    bf16* aout = (bf16*)ws;  ws += (size_t)NB * LQ * DQ * 2;
    bf16* yb   = (bf16*)ws;  ws += (size_t)NB * LKV * DKV * 2;
    bf16* xb   = aout;  // alias: xb dead (last read = Q-proj) before attn writes aout

    int nx8 = NB * LQ * DQ / 8, ny8 = NB * LKV * DKV / 8;
    prep<<<dim3(32, 32, 5), dim3(32, 8), 0, stream>>>(
        Wq, Wk, Wv, Wo, Wq_t, Wk_t, Wv_t, Wo_t,
        x, y, xb, yb, nx8, nx8 + ny8);

    gemm_qkv<<<dim3(8, 96), 256, 0, stream>>>(
        xb, Wq_t, bq, qbuf, yb, Wk_t, bk, kbuf, Wv_t, bv, vT);

    rmsnorm_rope3<<<NB * (LQ + LKV) / 4, 256, 0, stream>>>(
        qbuf, kbuf, gq, gk, x_cos, x_sin, y_cos, y_sin);

    attn_kern<<<dim3(LQ / 128, NH, NB), 256, 0, stream>>>(qbuf, kbuf, vT, aout);

    gemm_o<<<dim3(DQ / 128, NB * LQ / 128), 256, 0, stream>>>(aout, Wo_t, bo, d_out);
}

// Round 4
// 248.453 us; speedup vs baseline: 1.2047x; 1.1386x over previous
//
#include <hip/hip_runtime.h>

typedef __bf16 bf16;
typedef __bf16 bf16x4 __attribute__((ext_vector_type(4)));
typedef __bf16 bf16x8 __attribute__((ext_vector_type(8)));
typedef float  f32x4  __attribute__((ext_vector_type(4)));
typedef float  f32x16 __attribute__((ext_vector_type(16)));
typedef unsigned u32x4 __attribute__((ext_vector_type(4)));

#define NH   16
#define HD   64
#define DQ   1024
#define DKV  768
#define LQ   4096
#define LKV  1024
#define NB   2

__device__ __forceinline__ f32x4 mfma16(bf16x8 a, bf16x8 b, f32x4 c) {
    return __builtin_amdgcn_mfma_f32_16x16x32_bf16(a, b, c, 0, 0, 0);
}
__device__ __forceinline__ f32x16 mfma32(bf16x8 a, bf16x8 b, f32x16 c) {
    return __builtin_amdgcn_mfma_f32_32x32x16_bf16(a, b, c, 0, 0, 0);
}

// exchange a.hi-lanes <-> b.lo-lanes: after call a = (a.lo, b.lo), b = (a.hi, b.hi)
__device__ __forceinline__ void plswap(unsigned &a, unsigned &b) {
#if __has_builtin(__builtin_amdgcn_permlane32_swap)
    auto r = __builtin_amdgcn_permlane32_swap(a, b, false, false);
    a = (unsigned)r[0]; b = (unsigned)r[1];
#else
    asm volatile("v_permlane32_swap_b32 %0, %1" : "+v"(a), "+v"(b));
#endif
}

// async global->LDS, 16B per lane; LDS dest wave-uniform base (HW adds lane*16)
#define GLDS16(g, l) __builtin_amdgcn_global_load_lds(                      \
    (const __attribute__((address_space(1))) void*)(g),                     \
    (__attribute__((address_space(3))) void*)(l), 16, 0, 0)

// ------- prep: 4 weight transposes (f32 KxN -> bf16 NxK) + x/y f32->bf16 -----
__global__ __launch_bounds__(256) void prep(
        const float* __restrict__ Wq, const float* __restrict__ Wk,
        const float* __restrict__ Wv, const float* __restrict__ Wo,
        bf16* __restrict__ Wq_t, bf16* __restrict__ Wk_t,
        bf16* __restrict__ Wv_t, bf16* __restrict__ Wo_t,
        const float* __restrict__ x, const float* __restrict__ y,
        bf16* __restrict__ xb, bf16* __restrict__ yb,
        int nx8, int ntot8) {
    if (blockIdx.z < 4) {
        __shared__ float tile[32][33];
        const float* in; bf16* out; int K;
        switch (blockIdx.z) {
            case 0:  in = Wq; out = Wq_t; K = DQ;  break;
            case 1:  in = Wk; out = Wk_t; K = DKV; break;
            case 2:  in = Wv; out = Wv_t; K = DKV; break;
            default: in = Wo; out = Wo_t; K = DQ;  break;
        }
        int n0 = blockIdx.x * 32, k0 = blockIdx.y * 32;
        if (k0 >= K) return;
        int tx = threadIdx.x, ty = threadIdx.y;  // (32,8)
        for (int yy = 0; yy < 32; yy += 8)
            tile[ty + yy][tx] = in[(size_t)(k0 + ty + yy) * DQ + n0 + tx];
        __syncthreads();
        for (int yy = 0; yy < 32; yy += 8)
            out[(size_t)(n0 + ty + yy) * K + k0 + tx] = (bf16)tile[tx][ty + yy];
    } else {
        int tid = threadIdx.y * 32 + threadIdx.x;
        int flat = (blockIdx.y * 32 + blockIdx.x) * 256 + tid;  // 0..262143
        for (int i = flat; i < ntot8; i += 32 * 32 * 256) {
            const float* in; bf16* out; int j;
            if (i < nx8) { in = x; out = xb; j = i; }
            else         { in = y; out = yb; j = i - nx8; }
            float4 a0 = ((const float4*)in)[(size_t)j * 2];
            float4 a1 = ((const float4*)in)[(size_t)j * 2 + 1];
            bf16x8 v = {(bf16)a0.x, (bf16)a0.y, (bf16)a0.z, (bf16)a0.w,
                        (bf16)a1.x, (bf16)a1.y, (bf16)a1.z, (bf16)a1.w};
            ((bf16x8*)out)[j] = v;
        }
    }
}

// ------- 128x128-tile GEMM body: C = A(MxK,bf16) @ Bt(NxK,bf16)^T + bias -----
// Minimum 2-phase pipeline (guide T3 recipe, no inline asm): double-buffered
// LDS; STAGE(next) issued BEFORE computing current so the in-flight loads hide
// under the MFMA phase; one __syncthreads per iteration AFTER compute (its
// implicit vmcnt(0) drain is short since loads had the compute phase to land;
// it also protects buffer reuse at t+1's STAGE).
// LDS tiles use a 16B-slot XOR swizzle (slot p of row r holds logical p^(r&3)):
// staging source pre-swizzled (GLDS dest stays linear, rule #21), fragment
// reads apply the same XOR -> 8-way bank conflict drops to 4-way.
// MODE 0: C bf16 row-major. MODE 1: V-transposed bf16 vT[b,h,d,kv]. MODE 2: C f32.
template <int MODE>
__device__ __forceinline__ void gemm_body(bf16* __restrict__ sm,
                                          const bf16* __restrict__ A,
                                          const bf16* __restrict__ Bt,
                                          const float* __restrict__ bias,
                                          void* __restrict__ Cv,
                                          int N, int K, int m0, int n0) {
    bf16* As = sm;              // [2][128*32]
    bf16* Bs = sm + 2 * 4096;   // [2][128*32]
    int tid  = threadIdx.x;
    int lane = tid & 63, w = tid >> 6;
    int quad = lane >> 4, l15 = lane & 15;
    int wm = (w >> 1) * 64, wn = (w & 1) * 64;
    int srow = tid >> 2;
    int scol = ((tid & 3) ^ (srow & 3)) * 8;     // pre-swizzled global source slot
    const bf16* Ag = &A [(size_t)(m0 + srow) * K + scol];
    const bf16* Bg = &Bt[(size_t)(n0 + srow) * K + scol];
    int woff = w * 512;
    int fcol = ((quad ^ (l15 & 3)) * 8);         // swizzled read slot (row&3==l15&3)

    f32x4 acc[4][4] = {};
    int nit = K >> 5;

#define STAGE(buf, kk) do {                                              \
        int k0_ = (kk) << 5;                                             \
        bf16* a_ = As + (buf) * 4096 + woff;                             \
        bf16* b_ = Bs + (buf) * 4096 + woff;                             \
        GLDS16(Ag + k0_,                  a_);                           \
        GLDS16(Ag + (size_t)64 * K + k0_, a_ + 2048);                    \
        GLDS16(Bg + k0_,                  b_);                           \
        GLDS16(Bg + (size_t)64 * K + k0_, b_ + 2048);                    \
    } while (0)

    STAGE(0, 0);
    __syncthreads();                  // implicit vmcnt(0): tile 0 landed

    for (int t = 0; t < nit; t++) {
        int cur = t & 1;
        if (t + 1 < nit) STAGE(cur ^ 1, t + 1);   // issue next-tile loads FIRST
        const bf16* Ac = As + cur * 4096;
        const bf16* Bc = Bs + cur * 4096;
        bf16x8 af[4], bfr[4];
#pragma unroll
        for (int i = 0; i < 4; i++)
            af[i] = *(const bf16x8*)&Ac[(wm + i * 16 + l15) * 32 + fcol];
#pragma unroll
        for (int j = 0; j < 4; j++)
            bfr[j] = *(const bf16x8*)&Bc[(wn + j * 16 + l15) * 32 + fcol];
#pragma unroll
        for (int i = 0; i < 4; i++)
#pragma unroll
            for (int j = 0; j < 4; j++)
                acc[i][j] = mfma16(af[i], bfr[j], acc[i][j]);
        __syncthreads();              // drains next-tile loads + guards reuse
    }
#undef STAGE

    bf16*  Cb = (bf16*)Cv;
    float* Cf = (float*)Cv;
#pragma unroll
    for (int i = 0; i < 4; i++)
#pragma unroll
        for (int j = 0; j < 4; j++) {
            int col = n0 + wn + j * 16 + l15;
            float bcol = bias[col];
            if (MODE == 1) {
                int rowb = m0 + wm + i * 16 + quad * 4;      // 4 consecutive kv
                int bb = rowb >> 10, kv = rowb & 1023;       // LKV = 1024
                int h = col >> 6, d = col & 63;
                bf16x4 val = {(bf16)(acc[i][j][0] + bcol), (bf16)(acc[i][j][1] + bcol),
                              (bf16)(acc[i][j][2] + bcol), (bf16)(acc[i][j][3] + bcol)};
                *(bf16x4*)&Cb[(((size_t)(bb * NH + h) * HD) + d) * LKV + kv] = val;
            } else {
#pragma unroll
                for (int r = 0; r < 4; r++) {
                    int row = m0 + wm + i * 16 + quad * 4 + r;
                    float v = acc[i][j][r] + bcol;
                    if (MODE == 2) Cf[(size_t)row * N + col] = v;
                    else           Cb[(size_t)row * N + col] = (bf16)v;
                }
            }
        }
}

// one launch, XCD-swizzled work map: yt<64 -> Q-proj, 64..79 -> K, 80..95 -> V
__global__ __launch_bounds__(256, 3) void gemm_qkv(
        const bf16* xb, const bf16* Wq_t, const float* bq, bf16* qbuf,
        const bf16* yb, const bf16* Wk_t, const float* bk, bf16* kbuf,
        const bf16* Wv_t, const float* bv, bf16* vT) {
    __shared__ bf16 sm[4 * 4096];
    int lin  = blockIdx.y * 8 + blockIdx.x;        // dispatch index, 768 blocks
    int work = (lin & 7) * 96 + (lin >> 3);        // bijective (768 % 8 == 0)
    int xt = work & 7, yt = work >> 3;
    if (yt < 64)      gemm_body<0>(sm, xb, Wq_t, bq, qbuf, DQ, DQ,  yt * 128,        xt * 128);
    else if (yt < 80) gemm_body<0>(sm, yb, Wk_t, bk, kbuf, DQ, DKV, (yt - 64) * 128, xt * 128);
    else              gemm_body<1>(sm, yb, Wv_t, bv, vT,   DQ, DKV, (yt - 80) * 128, xt * 128);
}
__global__ __launch_bounds__(256, 3) void gemm_o(const bf16* A, const bf16* Bt,
                                                 const float* bias, void* Cv) {
    __shared__ bf16 sm[4 * 4096];
    int lin  = blockIdx.y * 8 + blockIdx.x;        // 512 blocks
    int work = (lin & 7) * 64 + (lin >> 3);
    int xt = work & 7, yt = work >> 3;
    gemm_body<2>(sm, A, Bt, bias, Cv, DQ, DQ, yt * 128, xt * 128);
}

// ------- RMSNorm + RoPE, one wave per row, register-resident -----------------
__global__ __launch_bounds__(256) void rmsnorm_rope3(bf16* __restrict__ qb,
                                                     bf16* __restrict__ kb,
                                                     const float* __restrict__ gq,
                                                     const float* __restrict__ gk,
                                                     const float* __restrict__ xc,
                                                     const float* __restrict__ xs,
                                                     const float* __restrict__ yc,
                                                     const float* __restrict__ ys) {
    int w = threadIdx.x >> 6, lane = threadIdx.x & 63;
    int row = blockIdx.x * 4 + w;
    bf16* t; const float *g, *cs, *sn;
    if (row < NB * LQ) {
        t = qb + (size_t)row * DQ; g = gq;
        cs = xc + (size_t)row * HD; sn = xs + (size_t)row * HD;
    } else {
        int r2 = row - NB * LQ;
        t = kb + (size_t)r2 * DQ; g = gk;
        cs = yc + (size_t)r2 * HD; sn = ys + (size_t)r2 * HD;
    }
    int c0 = lane * 16;
    bf16x8 a0 = *(const bf16x8*)&t[c0];
    bf16x8 a1 = *(const bf16x8*)&t[c0 + 8];
    float vv[16], ss = 0.f;
#pragma unroll
    for (int j = 0; j < 8; j++) { vv[j] = (float)a0[j]; vv[8 + j] = (float)a1[j]; }
#pragma unroll
    for (int j = 0; j < 16; j++) ss += vv[j] * vv[j];
#pragma unroll
    for (int off = 32; off >= 1; off >>= 1) ss += __shfl_xor(ss, off, 64);
    float rms = rsqrtf(ss * (1.0f / 1024.0f) + 1e-6f);
    float nv[16];
#pragma unroll
    for (int j = 0; j < 16; j++) nv[j] = vv[j] * rms * g[c0 + j];
    int d0 = (lane & 3) * 16;
    float sgn = (lane & 2) ? 1.f : -1.f;   // d<32 -> -partner, d>=32 -> +partner
    bf16x8 o0, o1;
#pragma unroll
    for (int j = 0; j < 16; j++) {
        float pv = __shfl_xor(nv[j], 2, 64);
        float r = nv[j] * cs[d0 + j] + sgn * pv * sn[d0 + j];
        if (j < 8) o0[j] = (bf16)r; else o1[j - 8] = (bf16)r;
    }
    *(bf16x8*)&t[c0]     = o0;
    *(bf16x8*)&t[c0 + 8] = o1;
}

// ------- flash attention v6: 32x32 MFMA, in-register P, GLDS16 staging -------
// block = (b,h,128 q rows); wave w owns q rows w*32..w*32+31 (q = l31, both
// hi-halves of the wave hold the same q, disjoint kv/d quarters).
// K/V chunk (64 kv) double-buffered in UNPADDED [64][64] LDS staged by
// global_load_lds with XOR-swizzled per-lane SOURCE addresses (rule #21).
// P never touches LDS: 32x32 C-layout keeps a full P row per lane; the
// B-operand fragment is built with v_cvt_pk_bf16_f32 + permlane32_swap (T12).
__global__ __launch_bounds__(256, 4) void attn_kern(const bf16* __restrict__ q,
                                                    const bf16* __restrict__ k,
                                                    const bf16* __restrict__ vT,
                                                    bf16* __restrict__ o) {
    __shared__ bf16 Ks[2][64][64];          // [buf][kv][d]   (swizzled slots)
    __shared__ bf16 Vs[2][64][64];          // [buf][d][kv]   (swizzled slots)
    int tid = threadIdx.x, w = tid >> 6, lane = tid & 63;
    int l31 = lane & 31, hi = lane >> 5;
    // XCD swizzle over 1024 blocks: same-(b,h) blocks share 256KB K/V in L2
    int lin  = blockIdx.x + (blockIdx.y << 5) + (blockIdx.z << 9);
    int work = (lin & 7) * 128 + (lin >> 3);
    int qt = work & 31, h = (work >> 5) & 15, b = work >> 9;
    int qrow = qt * 128 + w * 32 + l31;
    int sw8 = (l31 & 7) << 3;               // read-side element XOR (16B granular)

    // Q fragments (B-operand): col=q=l31, k(d) = kc*16 + hi*8 + e; fold 1/8 scale
    bf16x8 qf[4];
    {
        const bf16* qg = &q[((size_t)(b * LQ) + qrow) * DQ + h * HD + hi * 8];
#pragma unroll
        for (int kc = 0; kc < 4; kc++) {
            bf16x8 tq = *(const bf16x8*)(qg + kc * 16);
#pragma unroll
            for (int e = 0; e < 8; e++) tq[e] = (bf16)((float)tq[e] * 0.125f);
            qf[kc] = tq;
        }
    }

    // staging: wave w stages rows [w*16, w*16+16) of K (kv rows) and V (d rows).
    // each GLDS16 covers 8 rows: lane -> row rb+(lane>>3), dest slot lane&7;
    // source slot = (lane&7) ^ (row&7)  (inverse swizzle; (row+8)&7 == row&7)
    int rb = w * 16;
    int srow = rb + (lane >> 3);
    int sl = (lane & 7) ^ (srow & 7);
    const bf16* kg0 = &k[((size_t)(b * LKV) + srow) * DQ + h * HD + sl * 8];
    const bf16* vg0 = &vT[(((size_t)(b * NH + h) * HD) + srow) * LKV + sl * 8];

    GLDS16(kg0,                   &Ks[0][rb][0]);
    GLDS16(kg0 + (size_t)8 * DQ,  &Ks[0][rb + 8][0]);
    GLDS16(vg0,                   &Vs[0][rb][0]);
    GLDS16(vg0 + (size_t)8 * LKV, &Vs[0][rb + 8][0]);
    __syncthreads();

    f32x16 O0 = {}, O1 = {};
    float m_run = -1e30f, l_run = 0.f;

    for (int i = 0; i < 16; i++) {
        int cur = i & 1;
        if (i < 15) {                        // async prefetch of chunk i+1
            int nxt = cur ^ 1;
            size_t ko = (size_t)(i + 1) * 64 * DQ;
            int    vo = (i + 1) * 64;
            GLDS16(kg0 + ko,                   &Ks[nxt][rb][0]);
            GLDS16(kg0 + ko + (size_t)8 * DQ,  &Ks[nxt][rb + 8][0]);
            GLDS16(vg0 + vo,                   &Vs[nxt][rb][0]);
            GLDS16(vg0 + vo + (size_t)8 * LKV, &Vs[nxt][rb + 8][0]);
        }
#pragma unroll
        for (int t = 0; t < 2; t++) {
            // S^T tile (32 kv x 32 q): rows kv = t*32.., cols q = l31
            f32x16 S = {};
            {
                int krow = t * 32 + l31;
                __builtin_amdgcn_s_setprio(1);
#pragma unroll
                for (int kc = 0; kc < 4; kc++) {
                    bf16x8 kf = *(const bf16x8*)&Ks[cur][krow][(kc * 16 + hi * 8) ^ sw8];
                    S = mfma32(kf, qf[kc], S);
                }
                __builtin_amdgcn_s_setprio(0);
            }
            // row max (tree) + cross-half; T13 defer-max rescale
            float m01 = fmaxf(fmaxf(S[0], S[1]),  fmaxf(S[2], S[3]));
            float m23 = fmaxf(fmaxf(S[4], S[5]),  fmaxf(S[6], S[7]));
            float m45 = fmaxf(fmaxf(S[8], S[9]),  fmaxf(S[10], S[11]));
            float m67 = fmaxf(fmaxf(S[12], S[13]), fmaxf(S[14], S[15]));
            float pmax = fmaxf(fmaxf(m01, m23), fmaxf(m45, m67));
            pmax = fmaxf(pmax, __shfl_xor(pmax, 32, 64));
            if (!__all(pmax - m_run <= 8.f)) {
                float mn = fmaxf(m_run, pmax);
                float alpha = __expf(m_run - mn);
                m_run = mn; l_run *= alpha;
#pragma unroll
                for (int r = 0; r < 16; r++) { O0[r] *= alpha; O1[r] *= alpha; }
            }
            float rs = 0.f;
#pragma unroll
            for (int r = 0; r < 16; r++) { S[r] = __expf(S[r] - m_run); rs += S[r]; }
            rs += __shfl_xor(rs, 32, 64);
            l_run += rs;
            // pack P to bf16 pairs: dw[g*2+h] = (p[4g+2h], p[4g+2h+1])
            unsigned dw[8];
#pragma unroll
            for (int g = 0; g < 4; g++)
#pragma unroll
                for (int hh = 0; hh < 2; hh++) {
                    unsigned d_;
                    asm("v_cvt_pk_bf16_f32 %0, %1, %2"
                        : "=v"(d_) : "v"(S[4 * g + 2 * hh]), "v"(S[4 * g + 2 * hh + 1]));
                    dw[g * 2 + hh] = d_;
                }
            // B-fragments for PV: one permlane32_swap pair per K=16 chunk
#pragma unroll
            for (int kcl = 0; kcl < 2; kcl++) {
                int kc = t * 2 + kcl;
                unsigned a0 = dw[(2 * kcl) * 2 + 0], b0 = dw[(2 * kcl + 1) * 2 + 0];
                unsigned a1 = dw[(2 * kcl) * 2 + 1], b1 = dw[(2 * kcl + 1) * 2 + 1];
                plswap(a0, b0);
                plswap(a1, b1);
                u32x4 pw = {a0, a1, b0, b1};
                bf16x8 pb = __builtin_bit_cast(bf16x8, pw);
                int vcol = (kc * 16 + hi * 8) ^ sw8;
                bf16x8 vf0 = *(const bf16x8*)&Vs[cur][l31][vcol];
                bf16x8 vf1 = *(const bf16x8*)&Vs[cur][32 + l31][vcol];
                __builtin_amdgcn_s_setprio(1);
                O0 = mfma32(vf0, pb, O0);
                O1 = mfma32(vf1, pb, O1);
                __builtin_amdgcn_s_setprio(0);
            }
        }
        if (i < 15) __syncthreads();        // drains GLDS16 (vmcnt) + LDS reuse
    }

    float inv = 1.0f / l_run;
    size_t ob = ((size_t)(b * LQ) + qrow) * DQ + h * HD;
#pragma unroll
    for (int td = 0; td < 2; td++) {
        const f32x16& O = td ? O1 : O0;
#pragma unroll
        for (int g = 0; g < 4; g++) {
            bf16x4 ov = {(bf16)(O[4 * g + 0] * inv), (bf16)(O[4 * g + 1] * inv),
                         (bf16)(O[4 * g + 2] * inv), (bf16)(O[4 * g + 3] * inv)};
            *(bf16x4*)&o[ob + td * 32 + g * 8 + hi * 4] = ov;
        }
    }
}

// ---------------------------------------------------------------------------
extern "C" void kernel_launch(void* const* d_in, const int* in_sizes, int n_in,
                              void* d_out, int out_size, void* d_ws, size_t ws_size,
                              hipStream_t stream) {
    const float* x     = (const float*)d_in[0];
    const float* y     = (const float*)d_in[1];
    const float* x_cos = (const float*)d_in[2];
    const float* x_sin = (const float*)d_in[3];
    const float* y_cos = (const float*)d_in[4];
    const float* y_sin = (const float*)d_in[5];
    const float* Wq    = (const float*)d_in[6];
    const float* bq    = (const float*)d_in[7];
    const float* Wk    = (const float*)d_in[8];
    const float* bk    = (const float*)d_in[9];
    const float* Wv    = (const float*)d_in[10];
    const float* bv    = (const float*)d_in[11];
    const float* Wo    = (const float*)d_in[12];
    const float* bo    = (const float*)d_in[13];
    const float* gq    = (const float*)d_in[14];
    const float* gk    = (const float*)d_in[15];

    char* ws = (char*)d_ws;
    bf16* Wq_t = (bf16*)ws;  ws += (size_t)DQ * DQ * 2;
    bf16* Wk_t = (bf16*)ws;  ws += (size_t)DQ * DKV * 2;
    bf16* Wv_t = (bf16*)ws;  ws += (size_t)DQ * DKV * 2;
    bf16* Wo_t = (bf16*)ws;  ws += (size_t)DQ * DQ * 2;
    bf16* qbuf = (bf16*)ws;  ws += (size_t)NB * LQ * DQ * 2;
    bf16* kbuf = (bf16*)ws;  ws += (size_t)NB * LKV * DQ * 2;
    bf16* vT   = (bf16*)ws;  ws += (size_t)NB * NH * HD * LKV * 2;
    bf16* aout = (bf16*)ws;  ws += (size_t)NB * LQ * DQ * 2;
    bf16* yb   = (bf16*)ws;  ws += (size_t)NB * LKV * DKV * 2;
    bf16* xb   = aout;  // alias: xb dead (last read = Q-proj) before attn writes aout

    int nx8 = NB * LQ * DQ / 8, ny8 = NB * LKV * DKV / 8;
    prep<<<dim3(32, 32, 5), dim3(32, 8), 0, stream>>>(
        Wq, Wk, Wv, Wo, Wq_t, Wk_t, Wv_t, Wo_t,
        x, y, xb, yb, nx8, nx8 + ny8);

    gemm_qkv<<<dim3(8, 96), 256, 0, stream>>>(
        xb, Wq_t, bq, qbuf, yb, Wk_t, bk, kbuf, Wv_t, bv, vT);

    rmsnorm_rope3<<<NB * (LQ + LKV) / 4, 256, 0, stream>>>(
        qbuf, kbuf, gq, gk, x_cos, x_sin, y_cos, y_sin);

    attn_kern<<<dim3(LQ / 128, NH, NB), 256, 0, stream>>>(qbuf, kbuf, vT, aout);

    gemm_o<<<dim3(DQ / 128, NB * LQ / 128), 256, 0, stream>>>(aout, Wo_t, bo, d_out);
}

// Round 5
// 247.282 us; speedup vs baseline: 1.2104x; 1.0047x over previous
//
#include <hip/hip_runtime.h>

typedef __bf16 bf16;
typedef __bf16 bf16x4 __attribute__((ext_vector_type(4)));
typedef __bf16 bf16x8 __attribute__((ext_vector_type(8)));
typedef float  f32x4  __attribute__((ext_vector_type(4)));
typedef float  f32x16 __attribute__((ext_vector_type(16)));
typedef unsigned u32x4 __attribute__((ext_vector_type(4)));

#define NH   16
#define HD   64
#define DQ   1024
#define DKV  768
#define LQ   4096
#define LKV  1024
#define NB   2

__device__ __forceinline__ f32x4 mfma16(bf16x8 a, bf16x8 b, f32x4 c) {
    return __builtin_amdgcn_mfma_f32_16x16x32_bf16(a, b, c, 0, 0, 0);
}
__device__ __forceinline__ f32x16 mfma32(bf16x8 a, bf16x8 b, f32x16 c) {
    return __builtin_amdgcn_mfma_f32_32x32x16_bf16(a, b, c, 0, 0, 0);
}

// exchange a.hi-lanes <-> b.lo-lanes: after call a = (a.lo, b.lo), b = (a.hi, b.hi)
__device__ __forceinline__ void plswap(unsigned &a, unsigned &b) {
#if __has_builtin(__builtin_amdgcn_permlane32_swap)
    auto r = __builtin_amdgcn_permlane32_swap(a, b, false, false);
    a = (unsigned)r[0]; b = (unsigned)r[1];
#else
    asm volatile("v_permlane32_swap_b32 %0, %1" : "+v"(a), "+v"(b));
#endif
}

// async global->LDS, 16B per lane; LDS dest wave-uniform base (HW adds lane*16)
#define GLDS16(g, l) __builtin_amdgcn_global_load_lds(                      \
    (const __attribute__((address_space(1))) void*)(g),                     \
    (__attribute__((address_space(3))) void*)(l), 16, 0, 0)

// ------- prep: 4 weight transposes (f32 KxN -> bf16 NxK) + x/y f32->bf16 -----
__global__ __launch_bounds__(256) void prep(
        const float* __restrict__ Wq, const float* __restrict__ Wk,
        const float* __restrict__ Wv, const float* __restrict__ Wo,
        bf16* __restrict__ Wq_t, bf16* __restrict__ Wk_t,
        bf16* __restrict__ Wv_t, bf16* __restrict__ Wo_t,
        const float* __restrict__ x, const float* __restrict__ y,
        bf16* __restrict__ xb, bf16* __restrict__ yb,
        int nx8, int ntot8) {
    if (blockIdx.z < 4) {
        __shared__ float tile[32][33];
        const float* in; bf16* out; int K;
        switch (blockIdx.z) {
            case 0:  in = Wq; out = Wq_t; K = DQ;  break;
            case 1:  in = Wk; out = Wk_t; K = DKV; break;
            case 2:  in = Wv; out = Wv_t; K = DKV; break;
            default: in = Wo; out = Wo_t; K = DQ;  break;
        }
        int n0 = blockIdx.x * 32, k0 = blockIdx.y * 32;
        if (k0 >= K) return;
        int tx = threadIdx.x, ty = threadIdx.y;  // (32,8)
        for (int yy = 0; yy < 32; yy += 8)
            tile[ty + yy][tx] = in[(size_t)(k0 + ty + yy) * DQ + n0 + tx];
        __syncthreads();
        for (int yy = 0; yy < 32; yy += 8)
            out[(size_t)(n0 + ty + yy) * K + k0 + tx] = (bf16)tile[tx][ty + yy];
    } else {
        int tid = threadIdx.y * 32 + threadIdx.x;
        int flat = (blockIdx.y * 32 + blockIdx.x) * 256 + tid;  // 0..262143
        for (int i = flat; i < ntot8; i += 32 * 32 * 256) {
            const float* in; bf16* out; int j;
            if (i < nx8) { in = x; out = xb; j = i; }
            else         { in = y; out = yb; j = i - nx8; }
            float4 a0 = ((const float4*)in)[(size_t)j * 2];
            float4 a1 = ((const float4*)in)[(size_t)j * 2 + 1];
            bf16x8 v = {(bf16)a0.x, (bf16)a0.y, (bf16)a0.z, (bf16)a0.w,
                        (bf16)a1.x, (bf16)a1.y, (bf16)a1.z, (bf16)a1.w};
            ((bf16x8*)out)[j] = v;
        }
    }
}

// ------- 128x128-tile GEMM body: C = A(MxK,bf16) @ Bt(NxK,bf16)^T + bias -----
// Minimum 2-phase pipeline (guide T3 recipe, no inline asm): double-buffered
// LDS; STAGE(next) issued BEFORE computing current so the in-flight loads hide
// under the MFMA phase; one __syncthreads per iteration AFTER compute (its
// implicit vmcnt(0) drain is short since loads had the compute phase to land;
// it also protects buffer reuse at t+1's STAGE).
// LDS tiles use a 16B-slot XOR swizzle (slot p of row r holds logical p^(r&3)):
// staging source pre-swizzled (GLDS dest stays linear, rule #21), fragment
// reads apply the same XOR -> 8-way bank conflict drops to 4-way.
// MODE 0: C bf16 row-major. MODE 1: V-transposed bf16 vT[b,h,d,kv]. MODE 2: C f32.
template <int MODE>
__device__ __forceinline__ void gemm_body(bf16* __restrict__ sm,
                                          const bf16* __restrict__ A,
                                          const bf16* __restrict__ Bt,
                                          const float* __restrict__ bias,
                                          void* __restrict__ Cv,
                                          int N, int K, int m0, int n0) {
    bf16* As = sm;              // [2][128*32]
    bf16* Bs = sm + 2 * 4096;   // [2][128*32]
    int tid  = threadIdx.x;
    int lane = tid & 63, w = tid >> 6;
    int quad = lane >> 4, l15 = lane & 15;
    int wm = (w >> 1) * 64, wn = (w & 1) * 64;
    int srow = tid >> 2;
    int scol = ((tid & 3) ^ (srow & 3)) * 8;     // pre-swizzled global source slot
    const bf16* Ag = &A [(size_t)(m0 + srow) * K + scol];
    const bf16* Bg = &Bt[(size_t)(n0 + srow) * K + scol];
    int woff = w * 512;
    int fcol = ((quad ^ (l15 & 3)) * 8);         // swizzled read slot (row&3==l15&3)

    f32x4 acc[4][4] = {};
    int nit = K >> 5;

#define STAGE(buf, kk) do {                                              \
        int k0_ = (kk) << 5;                                             \
        bf16* a_ = As + (buf) * 4096 + woff;                             \
        bf16* b_ = Bs + (buf) * 4096 + woff;                             \
        GLDS16(Ag + k0_,                  a_);                           \
        GLDS16(Ag + (size_t)64 * K + k0_, a_ + 2048);                    \
        GLDS16(Bg + k0_,                  b_);                           \
        GLDS16(Bg + (size_t)64 * K + k0_, b_ + 2048);                    \
    } while (0)

    STAGE(0, 0);
    __syncthreads();                  // implicit vmcnt(0): tile 0 landed

    for (int t = 0; t < nit; t++) {
        int cur = t & 1;
        if (t + 1 < nit) STAGE(cur ^ 1, t + 1);   // issue next-tile loads FIRST
        const bf16* Ac = As + cur * 4096;
        const bf16* Bc = Bs + cur * 4096;
        bf16x8 af[4], bfr[4];
#pragma unroll
        for (int i = 0; i < 4; i++)
            af[i] = *(const bf16x8*)&Ac[(wm + i * 16 + l15) * 32 + fcol];
#pragma unroll
        for (int j = 0; j < 4; j++)
            bfr[j] = *(const bf16x8*)&Bc[(wn + j * 16 + l15) * 32 + fcol];
#pragma unroll
        for (int i = 0; i < 4; i++)
#pragma unroll
            for (int j = 0; j < 4; j++)
                acc[i][j] = mfma16(af[i], bfr[j], acc[i][j]);
        __syncthreads();              // drains next-tile loads + guards reuse
    }
#undef STAGE

    bf16*  Cb = (bf16*)Cv;
    float* Cf = (float*)Cv;
#pragma unroll
    for (int i = 0; i < 4; i++)
#pragma unroll
        for (int j = 0; j < 4; j++) {
            int col = n0 + wn + j * 16 + l15;
            float bcol = bias[col];
            if (MODE == 1) {
                int rowb = m0 + wm + i * 16 + quad * 4;      // 4 consecutive kv
                int bb = rowb >> 10, kv = rowb & 1023;       // LKV = 1024
                int h = col >> 6, d = col & 63;
                bf16x4 val = {(bf16)(acc[i][j][0] + bcol), (bf16)(acc[i][j][1] + bcol),
                              (bf16)(acc[i][j][2] + bcol), (bf16)(acc[i][j][3] + bcol)};
                *(bf16x4*)&Cb[(((size_t)(bb * NH + h) * HD) + d) * LKV + kv] = val;
            } else {
#pragma unroll
                for (int r = 0; r < 4; r++) {
                    int row = m0 + wm + i * 16 + quad * 4 + r;
                    float v = acc[i][j][r] + bcol;
                    if (MODE == 2) Cf[(size_t)row * N + col] = v;
                    else           Cb[(size_t)row * N + col] = (bf16)v;
                }
            }
        }
}

// one launch, XCD-swizzled work map: yt<64 -> Q-proj, 64..79 -> K, 80..95 -> V
__global__ __launch_bounds__(256, 3) void gemm_qkv(
        const bf16* xb, const bf16* Wq_t, const float* bq, bf16* qbuf,
        const bf16* yb, const bf16* Wk_t, const float* bk, bf16* kbuf,
        const bf16* Wv_t, const float* bv, bf16* vT) {
    __shared__ bf16 sm[4 * 4096];
    int lin  = blockIdx.y * 8 + blockIdx.x;        // dispatch index, 768 blocks
    int work = (lin & 7) * 96 + (lin >> 3);        // bijective (768 % 8 == 0)
    int xt = work & 7, yt = work >> 3;
    if (yt < 64)      gemm_body<0>(sm, xb, Wq_t, bq, qbuf, DQ, DQ,  yt * 128,        xt * 128);
    else if (yt < 80) gemm_body<0>(sm, yb, Wk_t, bk, kbuf, DQ, DKV, (yt - 64) * 128, xt * 128);
    else              gemm_body<1>(sm, yb, Wv_t, bv, vT,   DQ, DKV, (yt - 80) * 128, xt * 128);
}
__global__ __launch_bounds__(256, 3) void gemm_o(const bf16* A, const bf16* Bt,
                                                 const float* bias, void* Cv) {
    __shared__ bf16 sm[4 * 4096];
    int lin  = blockIdx.y * 8 + blockIdx.x;        // 512 blocks
    int work = (lin & 7) * 64 + (lin >> 3);
    int xt = work & 7, yt = work >> 3;
    gemm_body<2>(sm, A, Bt, bias, Cv, DQ, DQ, yt * 128, xt * 128);
}

// ------- RMSNorm + RoPE, one wave per row, register-resident -----------------
__global__ __launch_bounds__(256) void rmsnorm_rope3(bf16* __restrict__ qb,
                                                     bf16* __restrict__ kb,
                                                     const float* __restrict__ gq,
                                                     const float* __restrict__ gk,
                                                     const float* __restrict__ xc,
                                                     const float* __restrict__ xs,
                                                     const float* __restrict__ yc,
                                                     const float* __restrict__ ys) {
    int w = threadIdx.x >> 6, lane = threadIdx.x & 63;
    int row = blockIdx.x * 4 + w;
    bf16* t; const float *g, *cs, *sn;
    if (row < NB * LQ) {
        t = qb + (size_t)row * DQ; g = gq;
        cs = xc + (size_t)row * HD; sn = xs + (size_t)row * HD;
    } else {
        int r2 = row - NB * LQ;
        t = kb + (size_t)r2 * DQ; g = gk;
        cs = yc + (size_t)r2 * HD; sn = ys + (size_t)r2 * HD;
    }
    int c0 = lane * 16;
    bf16x8 a0 = *(const bf16x8*)&t[c0];
    bf16x8 a1 = *(const bf16x8*)&t[c0 + 8];
    float vv[16], ss = 0.f;
#pragma unroll
    for (int j = 0; j < 8; j++) { vv[j] = (float)a0[j]; vv[8 + j] = (float)a1[j]; }
#pragma unroll
    for (int j = 0; j < 16; j++) ss += vv[j] * vv[j];
#pragma unroll
    for (int off = 32; off >= 1; off >>= 1) ss += __shfl_xor(ss, off, 64);
    float rms = rsqrtf(ss * (1.0f / 1024.0f) + 1e-6f);
    float nv[16];
#pragma unroll
    for (int j = 0; j < 16; j++) nv[j] = vv[j] * rms * g[c0 + j];
    int d0 = (lane & 3) * 16;
    float sgn = (lane & 2) ? 1.f : -1.f;   // d<32 -> -partner, d>=32 -> +partner
    bf16x8 o0, o1;
#pragma unroll
    for (int j = 0; j < 16; j++) {
        float pv = __shfl_xor(nv[j], 2, 64);
        float r = nv[j] * cs[d0 + j] + sgn * pv * sn[d0 + j];
        if (j < 8) o0[j] = (bf16)r; else o1[j - 8] = (bf16)r;
    }
    *(bf16x8*)&t[c0]     = o0;
    *(bf16x8*)&t[c0 + 8] = o1;
}

// ------- flash attention v7: 32x32 MFMA, in-register P, T15 double-pipe ------
// block = (b,h,128 q rows); wave w owns q rows w*32..w*32+31 (q = l31, both
// hi-halves of the wave hold the same q, disjoint kv/d quarters).
// K/V chunk (64 kv) double-buffered in UNPADDED [64][64] LDS staged by
// global_load_lds with XOR-swizzled per-lane SOURCE addresses (rule #21).
// P never touches LDS (T12: v_cvt_pk_bf16_f32 + permlane32_swap).
// T15: both S-tiles' MFMAs issue back-to-back; softmax(S0) on the VALU
// overlaps S1's MFMA drain; softmax(S1) overlaps PV(t0)'s MFMAs.
__device__ __forceinline__ void softmax_pack(f32x16 &S, float &m_run, float &l_run,
                                             f32x16 &O0, f32x16 &O1, unsigned dw[8]) {
    // row max (max3-friendly chains) + cross-half; T13 defer-max rescale
    float a0 = fmaxf(fmaxf(S[0],  S[1]),  S[2]);
    float a1 = fmaxf(fmaxf(S[3],  S[4]),  S[5]);
    float a2 = fmaxf(fmaxf(S[6],  S[7]),  S[8]);
    float a3 = fmaxf(fmaxf(S[9],  S[10]), S[11]);
    float a4 = fmaxf(fmaxf(S[12], S[13]), S[14]);
    float pmax = fmaxf(fmaxf(fmaxf(a0, a1), fmaxf(a2, a3)), fmaxf(a4, S[15]));
    pmax = fmaxf(pmax, __shfl_xor(pmax, 32, 64));
    if (!__all(pmax - m_run <= 8.f)) {
        float mn = fmaxf(m_run, pmax);
        float alpha = __expf(m_run - mn);
        m_run = mn; l_run *= alpha;
#pragma unroll
        for (int r = 0; r < 16; r++) { O0[r] *= alpha; O1[r] *= alpha; }
    }
    float rs = 0.f;
#pragma unroll
    for (int r = 0; r < 16; r++) { S[r] = __expf(S[r] - m_run); rs += S[r]; }
    rs += __shfl_xor(rs, 32, 64);
    l_run += rs;
    // pack P to bf16 pairs: dw[g*2+h] = (p[4g+2h], p[4g+2h+1])
#pragma unroll
    for (int g = 0; g < 4; g++)
#pragma unroll
        for (int hh = 0; hh < 2; hh++) {
            unsigned d_;
            asm("v_cvt_pk_bf16_f32 %0, %1, %2"
                : "=v"(d_) : "v"(S[4 * g + 2 * hh]), "v"(S[4 * g + 2 * hh + 1]));
            dw[g * 2 + hh] = d_;
        }
}

__global__ __launch_bounds__(256, 4) void attn_kern(const bf16* __restrict__ q,
                                                    const bf16* __restrict__ k,
                                                    const bf16* __restrict__ vT,
                                                    bf16* __restrict__ o) {
    __shared__ bf16 Ks[2][64][64];          // [buf][kv][d]   (swizzled slots)
    __shared__ bf16 Vs[2][64][64];          // [buf][d][kv]   (swizzled slots)
    int tid = threadIdx.x, w = tid >> 6, lane = tid & 63;
    int l31 = lane & 31, hi = lane >> 5;
    // XCD swizzle over 1024 blocks: same-(b,h) blocks share 256KB K/V in L2
    int lin  = blockIdx.x + (blockIdx.y << 5) + (blockIdx.z << 9);
    int work = (lin & 7) * 128 + (lin >> 3);
    int qt = work & 31, h = (work >> 5) & 15, b = work >> 9;
    int qrow = qt * 128 + w * 32 + l31;
    int sw8 = (l31 & 7) << 3;               // read-side element XOR (16B granular)

    // Q fragments (B-operand): col=q=l31, k(d) = kc*16 + hi*8 + e; fold 1/8 scale
    bf16x8 qf[4];
    {
        const bf16* qg = &q[((size_t)(b * LQ) + qrow) * DQ + h * HD + hi * 8];
#pragma unroll
        for (int kc = 0; kc < 4; kc++) {
            bf16x8 tq = *(const bf16x8*)(qg + kc * 16);
#pragma unroll
            for (int e = 0; e < 8; e++) tq[e] = (bf16)((float)tq[e] * 0.125f);
            qf[kc] = tq;
        }
    }

    // staging: wave w stages rows [w*16, w*16+16) of K (kv rows) and V (d rows).
    // each GLDS16 covers 8 rows: lane -> row rb+(lane>>3), dest slot lane&7;
    // source slot = (lane&7) ^ (row&7)  (inverse swizzle; (row+8)&7 == row&7)
    int rb = w * 16;
    int srow = rb + (lane >> 3);
    int sl = (lane & 7) ^ (srow & 7);
    const bf16* kg0 = &k[((size_t)(b * LKV) + srow) * DQ + h * HD + sl * 8];
    const bf16* vg0 = &vT[(((size_t)(b * NH + h) * HD) + srow) * LKV + sl * 8];

    GLDS16(kg0,                   &Ks[0][rb][0]);
    GLDS16(kg0 + (size_t)8 * DQ,  &Ks[0][rb + 8][0]);
    GLDS16(vg0,                   &Vs[0][rb][0]);
    GLDS16(vg0 + (size_t)8 * LKV, &Vs[0][rb + 8][0]);
    __syncthreads();

    f32x16 O0 = {}, O1 = {};
    float m_run = -1e30f, l_run = 0.f;

    for (int i = 0; i < 16; i++) {
        int cur = i & 1;
        if (i < 15) {                        // async prefetch of chunk i+1
            int nxt = cur ^ 1;
            size_t ko = (size_t)(i + 1) * 64 * DQ;
            int    vo = (i + 1) * 64;
            GLDS16(kg0 + ko,                   &Ks[nxt][rb][0]);
            GLDS16(kg0 + ko + (size_t)8 * DQ,  &Ks[nxt][rb + 8][0]);
            GLDS16(vg0 + vo,                   &Vs[nxt][rb][0]);
            GLDS16(vg0 + vo + (size_t)8 * LKV, &Vs[nxt][rb + 8][0]);
        }
        // ---- S for BOTH tiles, MFMAs issued back-to-back (T15) ----
        f32x16 S0 = {}, S1 = {};
        __builtin_amdgcn_s_setprio(1);
#pragma unroll
        for (int kc = 0; kc < 4; kc++) {
            bf16x8 kf = *(const bf16x8*)&Ks[cur][l31][(kc * 16 + hi * 8) ^ sw8];
            S0 = mfma32(kf, qf[kc], S0);
        }
#pragma unroll
        for (int kc = 0; kc < 4; kc++) {
            bf16x8 kf = *(const bf16x8*)&Ks[cur][32 + l31][(kc * 16 + hi * 8) ^ sw8];
            S1 = mfma32(kf, qf[kc], S1);
        }
        __builtin_amdgcn_s_setprio(0);
        // ---- softmax(S0) on VALU overlaps S1's MFMA drain ----
        unsigned dw0[8], dw1[8];
        softmax_pack(S0, m_run, l_run, O0, O1, dw0);
        // ---- PV(t0): B-fragments via permlane32_swap, V from LDS ----
#pragma unroll
        for (int kcl = 0; kcl < 2; kcl++) {
            unsigned a0 = dw0[(2 * kcl) * 2 + 0], b0 = dw0[(2 * kcl + 1) * 2 + 0];
            unsigned a1 = dw0[(2 * kcl) * 2 + 1], b1 = dw0[(2 * kcl + 1) * 2 + 1];
            plswap(a0, b0);
            plswap(a1, b1);
            u32x4 pw = {a0, a1, b0, b1};
            bf16x8 pb = __builtin_bit_cast(bf16x8, pw);
            int vcol = (kcl * 16 + hi * 8) ^ sw8;
            bf16x8 vf0 = *(const bf16x8*)&Vs[cur][l31][vcol];
            bf16x8 vf1 = *(const bf16x8*)&Vs[cur][32 + l31][vcol];
            __builtin_amdgcn_s_setprio(1);
            O0 = mfma32(vf0, pb, O0);
            O1 = mfma32(vf1, pb, O1);
            __builtin_amdgcn_s_setprio(0);
        }
        // ---- softmax(S1) on VALU overlaps PV(t0)'s MFMAs ----
        softmax_pack(S1, m_run, l_run, O0, O1, dw1);
        // ---- PV(t1) ----
#pragma unroll
        for (int kcl = 0; kcl < 2; kcl++) {
            unsigned a0 = dw1[(2 * kcl) * 2 + 0], b0 = dw1[(2 * kcl + 1) * 2 + 0];
            unsigned a1 = dw1[(2 * kcl) * 2 + 1], b1 = dw1[(2 * kcl + 1) * 2 + 1];
            plswap(a0, b0);
            plswap(a1, b1);
            u32x4 pw = {a0, a1, b0, b1};
            bf16x8 pb = __builtin_bit_cast(bf16x8, pw);
            int vcol = ((2 + kcl) * 16 + hi * 8) ^ sw8;
            bf16x8 vf0 = *(const bf16x8*)&Vs[cur][l31][vcol];
            bf16x8 vf1 = *(const bf16x8*)&Vs[cur][32 + l31][vcol];
            __builtin_amdgcn_s_setprio(1);
            O0 = mfma32(vf0, pb, O0);
            O1 = mfma32(vf1, pb, O1);
            __builtin_amdgcn_s_setprio(0);
        }
        if (i < 15) __syncthreads();        // drains GLDS16 (vmcnt) + LDS reuse
    }

    float inv = 1.0f / l_run;
    size_t ob = ((size_t)(b * LQ) + qrow) * DQ + h * HD;
#pragma unroll
    for (int td = 0; td < 2; td++) {
        const f32x16& O = td ? O1 : O0;
#pragma unroll
        for (int g = 0; g < 4; g++) {
            bf16x4 ov = {(bf16)(O[4 * g + 0] * inv), (bf16)(O[4 * g + 1] * inv),
                         (bf16)(O[4 * g + 2] * inv), (bf16)(O[4 * g + 3] * inv)};
            *(bf16x4*)&o[ob + td * 32 + g * 8 + hi * 4] = ov;
        }
    }
}

// ---------------------------------------------------------------------------
extern "C" void kernel_launch(void* const* d_in, const int* in_sizes, int n_in,
                              void* d_out, int out_size, void* d_ws, size_t ws_size,
                              hipStream_t stream) {
    const float* x     = (const float*)d_in[0];
    const float* y     = (const float*)d_in[1];
    const float* x_cos = (const float*)d_in[2];
    const float* x_sin = (const float*)d_in[3];
    const float* y_cos = (const float*)d_in[4];
    const float* y_sin = (const float*)d_in[5];
    const float* Wq    = (const float*)d_in[6];
    const float* bq    = (const float*)d_in[7];
    const float* Wk    = (const float*)d_in[8];
    const float* bk    = (const float*)d_in[9];
    const float* Wv    = (const float*)d_in[10];
    const float* bv    = (const float*)d_in[11];
    const float* Wo    = (const float*)d_in[12];
    const float* bo    = (const float*)d_in[13];
    const float* gq    = (const float*)d_in[14];
    const float* gk    = (const float*)d_in[15];

    char* ws = (char*)d_ws;
    bf16* Wq_t = (bf16*)ws;  ws += (size_t)DQ * DQ * 2;
    bf16* Wk_t = (bf16*)ws;  ws += (size_t)DQ * DKV * 2;
    bf16* Wv_t = (bf16*)ws;  ws += (size_t)DQ * DKV * 2;
    bf16* Wo_t = (bf16*)ws;  ws += (size_t)DQ * DQ * 2;
    bf16* qbuf = (bf16*)ws;  ws += (size_t)NB * LQ * DQ * 2;
    bf16* kbuf = (bf16*)ws;  ws += (size_t)NB * LKV * DQ * 2;
    bf16* vT   = (bf16*)ws;  ws += (size_t)NB * NH * HD * LKV * 2;
    bf16* aout = (bf16*)ws;  ws += (size_t)NB * LQ * DQ * 2;
    bf16* yb   = (bf16*)ws;  ws += (size_t)NB * LKV * DKV * 2;
    bf16* xb   = aout;  // alias: xb dead (last read = Q-proj) before attn writes aout

    int nx8 = NB * LQ * DQ / 8, ny8 = NB * LKV * DKV / 8;
    prep<<<dim3(32, 32, 5), dim3(32, 8), 0, stream>>>(
        Wq, Wk, Wv, Wo, Wq_t, Wk_t, Wv_t, Wo_t,
        x, y, xb, yb, nx8, nx8 + ny8);

    gemm_qkv<<<dim3(8, 96), 256, 0, stream>>>(
        xb, Wq_t, bq, qbuf, yb, Wk_t, bk, kbuf, Wv_t, bv, vT);

    rmsnorm_rope3<<<NB * (LQ + LKV) / 4, 256, 0, stream>>>(
        qbuf, kbuf, gq, gk, x_cos, x_sin, y_cos, y_sin);

    attn_kern<<<dim3(LQ / 128, NH, NB), 256, 0, stream>>>(qbuf, kbuf, vT, aout);

    gemm_o<<<dim3(DQ / 128, NB * LQ / 128), 256, 0, stream>>>(aout, Wo_t, bo, d_out);
}

// Round 6
// 246.320 us; speedup vs baseline: 1.2152x; 1.0039x over previous
//
#include <hip/hip_runtime.h>

typedef __bf16 bf16;
typedef __bf16 bf16x4 __attribute__((ext_vector_type(4)));
typedef __bf16 bf16x8 __attribute__((ext_vector_type(8)));
typedef float  f32x4  __attribute__((ext_vector_type(4)));
typedef float  f32x16 __attribute__((ext_vector_type(16)));
typedef unsigned u32x4 __attribute__((ext_vector_type(4)));

#define NH   16
#define HD   64
#define DQ   1024
#define DKV  768
#define LQ   4096
#define LKV  1024
#define NB   2

__device__ __forceinline__ f32x4 mfma16(bf16x8 a, bf16x8 b, f32x4 c) {
    return __builtin_amdgcn_mfma_f32_16x16x32_bf16(a, b, c, 0, 0, 0);
}
__device__ __forceinline__ f32x16 mfma32(bf16x8 a, bf16x8 b, f32x16 c) {
    return __builtin_amdgcn_mfma_f32_32x32x16_bf16(a, b, c, 0, 0, 0);
}

// exchange a.hi-lanes <-> b.lo-lanes: after call a = (a.lo, b.lo), b = (a.hi, b.hi)
__device__ __forceinline__ void plswap(unsigned &a, unsigned &b) {
#if __has_builtin(__builtin_amdgcn_permlane32_swap)
    auto r = __builtin_amdgcn_permlane32_swap(a, b, false, false);
    a = (unsigned)r[0]; b = (unsigned)r[1];
#else
    asm volatile("v_permlane32_swap_b32 %0, %1" : "+v"(a), "+v"(b));
#endif
}

// cross-half (lane i <-> i+32) reduce via permlane32_swap — pure VALU, no DS op
__device__ __forceinline__ float xhalf_max(float v) {
    unsigned t = __builtin_bit_cast(unsigned, v), u = t;
    plswap(t, u);
    return fmaxf(__builtin_bit_cast(float, t), __builtin_bit_cast(float, u));
}
__device__ __forceinline__ float xhalf_add(float v) {
    unsigned t = __builtin_bit_cast(unsigned, v), u = t;
    plswap(t, u);
    return __builtin_bit_cast(float, t) + __builtin_bit_cast(float, u);
}

// tree reductions over a 16-reg fragment (depth ~5 vs serial 16)
__device__ __forceinline__ float vmax16(const f32x16& S) {
    float a = fmaxf(fmaxf(S[0],  S[1]),  fmaxf(S[2],  S[3]));
    float b = fmaxf(fmaxf(S[4],  S[5]),  fmaxf(S[6],  S[7]));
    float c = fmaxf(fmaxf(S[8],  S[9]),  fmaxf(S[10], S[11]));
    float d = fmaxf(fmaxf(S[12], S[13]), fmaxf(S[14], S[15]));
    return fmaxf(fmaxf(a, b), fmaxf(c, d));
}
__device__ __forceinline__ float vsum16(const f32x16& S) {
    float a = (S[0]  + S[1])  + (S[2]  + S[3]);
    float b = (S[4]  + S[5])  + (S[6]  + S[7]);
    float c = (S[8]  + S[9])  + (S[10] + S[11]);
    float d = (S[12] + S[13]) + (S[14] + S[15]);
    return (a + b) + (c + d);
}

__device__ __forceinline__ void cvtpk16(const f32x16& S, unsigned dw[8]) {
#pragma unroll
    for (int g = 0; g < 4; g++)
#pragma unroll
        for (int hh = 0; hh < 2; hh++) {
            unsigned d_;
            asm("v_cvt_pk_bf16_f32 %0, %1, %2"
                : "=v"(d_) : "v"(S[4 * g + 2 * hh]), "v"(S[4 * g + 2 * hh + 1]));
            dw[g * 2 + hh] = d_;
        }
}

// async global->LDS, 16B per lane; LDS dest wave-uniform base (HW adds lane*16)
#define GLDS16(g, l) __builtin_amdgcn_global_load_lds(                      \
    (const __attribute__((address_space(1))) void*)(g),                     \
    (__attribute__((address_space(3))) void*)(l), 16, 0, 0)

// ------- prep: 4 weight transposes (f32 KxN -> bf16 NxK) + x/y f32->bf16 -----
__global__ __launch_bounds__(256) void prep(
        const float* __restrict__ Wq, const float* __restrict__ Wk,
        const float* __restrict__ Wv, const float* __restrict__ Wo,
        bf16* __restrict__ Wq_t, bf16* __restrict__ Wk_t,
        bf16* __restrict__ Wv_t, bf16* __restrict__ Wo_t,
        const float* __restrict__ x, const float* __restrict__ y,
        bf16* __restrict__ xb, bf16* __restrict__ yb,
        int nx8, int ntot8) {
    if (blockIdx.z < 4) {
        __shared__ float tile[32][33];
        const float* in; bf16* out; int K;
        switch (blockIdx.z) {
            case 0:  in = Wq; out = Wq_t; K = DQ;  break;
            case 1:  in = Wk; out = Wk_t; K = DKV; break;
            case 2:  in = Wv; out = Wv_t; K = DKV; break;
            default: in = Wo; out = Wo_t; K = DQ;  break;
        }
        int n0 = blockIdx.x * 32, k0 = blockIdx.y * 32;
        if (k0 >= K) return;
        int tx = threadIdx.x, ty = threadIdx.y;  // (32,8)
        for (int yy = 0; yy < 32; yy += 8)
            tile[ty + yy][tx] = in[(size_t)(k0 + ty + yy) * DQ + n0 + tx];
        __syncthreads();
        for (int yy = 0; yy < 32; yy += 8)
            out[(size_t)(n0 + ty + yy) * K + k0 + tx] = (bf16)tile[tx][ty + yy];
    } else {
        int tid = threadIdx.y * 32 + threadIdx.x;
        int flat = (blockIdx.y * 32 + blockIdx.x) * 256 + tid;  // 0..262143
        for (int i = flat; i < ntot8; i += 32 * 32 * 256) {
            const float* in; bf16* out; int j;
            if (i < nx8) { in = x; out = xb; j = i; }
            else         { in = y; out = yb; j = i - nx8; }
            float4 a0 = ((const float4*)in)[(size_t)j * 2];
            float4 a1 = ((const float4*)in)[(size_t)j * 2 + 1];
            bf16x8 v = {(bf16)a0.x, (bf16)a0.y, (bf16)a0.z, (bf16)a0.w,
                        (bf16)a1.x, (bf16)a1.y, (bf16)a1.z, (bf16)a1.w};
            ((bf16x8*)out)[j] = v;
        }
    }
}

// ------- 128x128-tile GEMM body: C = A(MxK,bf16) @ Bt(NxK,bf16)^T + bias -----
// Minimum 2-phase pipeline (guide T3 recipe, no inline asm): double-buffered
// LDS; STAGE(next) issued BEFORE computing current so the in-flight loads hide
// under the MFMA phase; one __syncthreads per iteration AFTER compute.
// LDS tiles use a 16B-slot XOR swizzle (slot p of row r holds logical p^(r&3)):
// staging source pre-swizzled (GLDS dest stays linear, rule #21), fragment
// reads apply the same XOR -> 8-way bank conflict drops to 4-way.
// MODE 0: C bf16 row-major. MODE 1: V-transposed bf16 vT[b,h,d,kv]. MODE 2: C f32.
template <int MODE>
__device__ __forceinline__ void gemm_body(bf16* __restrict__ sm,
                                          const bf16* __restrict__ A,
                                          const bf16* __restrict__ Bt,
                                          const float* __restrict__ bias,
                                          void* __restrict__ Cv,
                                          int N, int K, int m0, int n0) {
    bf16* As = sm;              // [2][128*32]
    bf16* Bs = sm + 2 * 4096;   // [2][128*32]
    int tid  = threadIdx.x;
    int lane = tid & 63, w = tid >> 6;
    int quad = lane >> 4, l15 = lane & 15;
    int wm = (w >> 1) * 64, wn = (w & 1) * 64;
    int srow = tid >> 2;
    int scol = ((tid & 3) ^ (srow & 3)) * 8;     // pre-swizzled global source slot
    const bf16* Ag = &A [(size_t)(m0 + srow) * K + scol];
    const bf16* Bg = &Bt[(size_t)(n0 + srow) * K + scol];
    int woff = w * 512;
    int fcol = ((quad ^ (l15 & 3)) * 8);         // swizzled read slot (row&3==l15&3)

    f32x4 acc[4][4] = {};
    int nit = K >> 5;

#define STAGE(buf, kk) do {                                              \
        int k0_ = (kk) << 5;                                             \
        bf16* a_ = As + (buf) * 4096 + woff;                             \
        bf16* b_ = Bs + (buf) * 4096 + woff;                             \
        GLDS16(Ag + k0_,                  a_);                           \
        GLDS16(Ag + (size_t)64 * K + k0_, a_ + 2048);                    \
        GLDS16(Bg + k0_,                  b_);                           \
        GLDS16(Bg + (size_t)64 * K + k0_, b_ + 2048);                    \
    } while (0)

    STAGE(0, 0);
    __syncthreads();                  // implicit vmcnt(0): tile 0 landed

    for (int t = 0; t < nit; t++) {
        int cur = t & 1;
        if (t + 1 < nit) STAGE(cur ^ 1, t + 1);   // issue next-tile loads FIRST
        const bf16* Ac = As + cur * 4096;
        const bf16* Bc = Bs + cur * 4096;
        bf16x8 af[4], bfr[4];
#pragma unroll
        for (int i = 0; i < 4; i++)
            af[i] = *(const bf16x8*)&Ac[(wm + i * 16 + l15) * 32 + fcol];
#pragma unroll
        for (int j = 0; j < 4; j++)
            bfr[j] = *(const bf16x8*)&Bc[(wn + j * 16 + l15) * 32 + fcol];
#pragma unroll
        for (int i = 0; i < 4; i++)
#pragma unroll
            for (int j = 0; j < 4; j++)
                acc[i][j] = mfma16(af[i], bfr[j], acc[i][j]);
        __syncthreads();              // drains next-tile loads + guards reuse
    }
#undef STAGE

    bf16*  Cb = (bf16*)Cv;
    float* Cf = (float*)Cv;
#pragma unroll
    for (int i = 0; i < 4; i++)
#pragma unroll
        for (int j = 0; j < 4; j++) {
            int col = n0 + wn + j * 16 + l15;
            float bcol = bias[col];
            if (MODE == 1) {
                int rowb = m0 + wm + i * 16 + quad * 4;      // 4 consecutive kv
                int bb = rowb >> 10, kv = rowb & 1023;       // LKV = 1024
                int h = col >> 6, d = col & 63;
                bf16x4 val = {(bf16)(acc[i][j][0] + bcol), (bf16)(acc[i][j][1] + bcol),
                              (bf16)(acc[i][j][2] + bcol), (bf16)(acc[i][j][3] + bcol)};
                *(bf16x4*)&Cb[(((size_t)(bb * NH + h) * HD) + d) * LKV + kv] = val;
            } else {
#pragma unroll
                for (int r = 0; r < 4; r++) {
                    int row = m0 + wm + i * 16 + quad * 4 + r;
                    float v = acc[i][j][r] + bcol;
                    if (MODE == 2) Cf[(size_t)row * N + col] = v;
                    else           Cb[(size_t)row * N + col] = (bf16)v;
                }
            }
        }
}

// one launch, XCD-swizzled work map: yt<64 -> Q-proj, 64..79 -> K, 80..95 -> V
__global__ __launch_bounds__(256, 3) void gemm_qkv(
        const bf16* xb, const bf16* Wq_t, const float* bq, bf16* qbuf,
        const bf16* yb, const bf16* Wk_t, const float* bk, bf16* kbuf,
        const bf16* Wv_t, const float* bv, bf16* vT) {
    __shared__ bf16 sm[4 * 4096];
    int lin  = blockIdx.y * 8 + blockIdx.x;        // dispatch index, 768 blocks
    int work = (lin & 7) * 96 + (lin >> 3);        // bijective (768 % 8 == 0)
    int xt = work & 7, yt = work >> 3;
    if (yt < 64)      gemm_body<0>(sm, xb, Wq_t, bq, qbuf, DQ, DQ,  yt * 128,        xt * 128);
    else if (yt < 80) gemm_body<0>(sm, yb, Wk_t, bk, kbuf, DQ, DKV, (yt - 64) * 128, xt * 128);
    else              gemm_body<1>(sm, yb, Wv_t, bv, vT,   DQ, DKV, (yt - 80) * 128, xt * 128);
}
__global__ __launch_bounds__(256, 3) void gemm_o(const bf16* A, const bf16* Bt,
                                                 const float* bias, void* Cv) {
    __shared__ bf16 sm[4 * 4096];
    int lin  = blockIdx.y * 8 + blockIdx.x;        // 512 blocks
    int work = (lin & 7) * 64 + (lin >> 3);
    int xt = work & 7, yt = work >> 3;
    gemm_body<2>(sm, A, Bt, bias, Cv, DQ, DQ, yt * 128, xt * 128);
}

// ------- RMSNorm + RoPE, one wave per row, register-resident -----------------
__global__ __launch_bounds__(256) void rmsnorm_rope3(bf16* __restrict__ qb,
                                                     bf16* __restrict__ kb,
                                                     const float* __restrict__ gq,
                                                     const float* __restrict__ gk,
                                                     const float* __restrict__ xc,
                                                     const float* __restrict__ xs,
                                                     const float* __restrict__ yc,
                                                     const float* __restrict__ ys) {
    int w = threadIdx.x >> 6, lane = threadIdx.x & 63;
    int row = blockIdx.x * 4 + w;
    bf16* t; const float *g, *cs, *sn;
    if (row < NB * LQ) {
        t = qb + (size_t)row * DQ; g = gq;
        cs = xc + (size_t)row * HD; sn = xs + (size_t)row * HD;
    } else {
        int r2 = row - NB * LQ;
        t = kb + (size_t)r2 * DQ; g = gk;
        cs = yc + (size_t)r2 * HD; sn = ys + (size_t)r2 * HD;
    }
    int c0 = lane * 16;
    bf16x8 a0 = *(const bf16x8*)&t[c0];
    bf16x8 a1 = *(const bf16x8*)&t[c0 + 8];
    float vv[16], ss = 0.f;
#pragma unroll
    for (int j = 0; j < 8; j++) { vv[j] = (float)a0[j]; vv[8 + j] = (float)a1[j]; }
#pragma unroll
    for (int j = 0; j < 16; j++) ss += vv[j] * vv[j];
#pragma unroll
    for (int off = 32; off >= 1; off >>= 1) ss += __shfl_xor(ss, off, 64);
    float rms = rsqrtf(ss * (1.0f / 1024.0f) + 1e-6f);
    float nv[16];
#pragma unroll
    for (int j = 0; j < 16; j++) nv[j] = vv[j] * rms * g[c0 + j];
    int d0 = (lane & 3) * 16;
    float sgn = (lane & 2) ? 1.f : -1.f;   // d<32 -> -partner, d>=32 -> +partner
    bf16x8 o0, o1;
#pragma unroll
    for (int j = 0; j < 16; j++) {
        float pv = __shfl_xor(nv[j], 2, 64);
        float r = nv[j] * cs[d0 + j] + sgn * pv * sn[d0 + j];
        if (j < 8) o0[j] = (bf16)r; else o1[j - 8] = (bf16)r;
    }
    *(bf16x8*)&t[c0]     = o0;
    *(bf16x8*)&t[c0 + 8] = o1;
}

// ------- flash attention v8: 32x32 MFMA, in-register P, single softmax64 -----
// block = (b,h,128 q rows); wave w owns q rows w*32..w*32+31 (q = l31, both
// hi-halves of the wave hold the same q, disjoint kv/d quarters).
// K/V chunk (64 kv) double-buffered in UNPADDED [64][64] LDS staged by
// global_load_lds with XOR-swizzled per-lane SOURCE addresses (rule #21).
// P never touches LDS (T12: v_cvt_pk_bf16_f32 + permlane32_swap).
// v8: ONE online-softmax per 64-kv chunk (merged over both 32-kv tiles),
// permlane-based cross-half reduces (no DS shuffles), tree reductions.
__global__ __launch_bounds__(256, 4) void attn_kern(const bf16* __restrict__ q,
                                                    const bf16* __restrict__ k,
                                                    const bf16* __restrict__ vT,
                                                    bf16* __restrict__ o) {
    __shared__ bf16 Ks[2][64][64];          // [buf][kv][d]   (swizzled slots)
    __shared__ bf16 Vs[2][64][64];          // [buf][d][kv]   (swizzled slots)
    int tid = threadIdx.x, w = tid >> 6, lane = tid & 63;
    int l31 = lane & 31, hi = lane >> 5;
    // XCD swizzle over 1024 blocks: same-(b,h) blocks share 256KB K/V in L2
    int lin  = blockIdx.x + (blockIdx.y << 5) + (blockIdx.z << 9);
    int work = (lin & 7) * 128 + (lin >> 3);
    int qt = work & 31, h = (work >> 5) & 15, b = work >> 9;
    int qrow = qt * 128 + w * 32 + l31;
    int sw8 = (l31 & 7) << 3;               // read-side element XOR (16B granular)

    // Q fragments (B-operand): col=q=l31, k(d) = kc*16 + hi*8 + e; fold 1/8 scale
    bf16x8 qf[4];
    {
        const bf16* qg = &q[((size_t)(b * LQ) + qrow) * DQ + h * HD + hi * 8];
#pragma unroll
        for (int kc = 0; kc < 4; kc++) {
            bf16x8 tq = *(const bf16x8*)(qg + kc * 16);
#pragma unroll
            for (int e = 0; e < 8; e++) tq[e] = (bf16)((float)tq[e] * 0.125f);
            qf[kc] = tq;
        }
    }

    // staging: wave w stages rows [w*16, w*16+16) of K (kv rows) and V (d rows).
    // each GLDS16 covers 8 rows: lane -> row rb+(lane>>3), dest slot lane&7;
    // source slot = (lane&7) ^ (row&7)  (inverse swizzle; (row+8)&7 == row&7)
    int rb = w * 16;
    int srow = rb + (lane >> 3);
    int sl = (lane & 7) ^ (srow & 7);
    const bf16* kg0 = &k[((size_t)(b * LKV) + srow) * DQ + h * HD + sl * 8];
    const bf16* vg0 = &vT[(((size_t)(b * NH + h) * HD) + srow) * LKV + sl * 8];

    GLDS16(kg0,                   &Ks[0][rb][0]);
    GLDS16(kg0 + (size_t)8 * DQ,  &Ks[0][rb + 8][0]);
    GLDS16(vg0,                   &Vs[0][rb][0]);
    GLDS16(vg0 + (size_t)8 * LKV, &Vs[0][rb + 8][0]);
    __syncthreads();

    f32x16 O0 = {}, O1 = {};
    float m_run = -1e30f, l_run = 0.f;

    for (int i = 0; i < 16; i++) {
        int cur = i & 1;
        if (i < 15) {                        // async prefetch of chunk i+1
            int nxt = cur ^ 1;
            size_t ko = (size_t)(i + 1) * 64 * DQ;
            int    vo = (i + 1) * 64;
            GLDS16(kg0 + ko,                   &Ks[nxt][rb][0]);
            GLDS16(kg0 + ko + (size_t)8 * DQ,  &Ks[nxt][rb + 8][0]);
            GLDS16(vg0 + vo,                   &Vs[nxt][rb][0]);
            GLDS16(vg0 + vo + (size_t)8 * LKV, &Vs[nxt][rb + 8][0]);
        }
        // ---- S for both 32-kv tiles, MFMAs back-to-back ----
        f32x16 S0 = {}, S1 = {};
        __builtin_amdgcn_s_setprio(1);
#pragma unroll
        for (int kc = 0; kc < 4; kc++) {
            bf16x8 kf0 = *(const bf16x8*)&Ks[cur][l31][(kc * 16 + hi * 8) ^ sw8];
            bf16x8 kf1 = *(const bf16x8*)&Ks[cur][32 + l31][(kc * 16 + hi * 8) ^ sw8];
            S0 = mfma32(kf0, qf[kc], S0);
            S1 = mfma32(kf1, qf[kc], S1);
        }
        __builtin_amdgcn_s_setprio(0);
        // ---- single online-softmax over the 64-kv chunk (T13 defer-max) ----
        float pmax = fmaxf(vmax16(S0), vmax16(S1));
        pmax = xhalf_max(pmax);
        if (!__all(pmax - m_run <= 8.f)) {
            float mn = fmaxf(m_run, pmax);
            float alpha = __expf(m_run - mn);
            m_run = mn; l_run *= alpha;
#pragma unroll
            for (int r = 0; r < 16; r++) { O0[r] *= alpha; O1[r] *= alpha; }
        }
#pragma unroll
        for (int r = 0; r < 16; r++) S0[r] = __expf(S0[r] - m_run);
#pragma unroll
        for (int r = 0; r < 16; r++) S1[r] = __expf(S1[r] - m_run);
        float rs = vsum16(S0) + vsum16(S1);
        l_run += xhalf_add(rs);
        // pack P to bf16 pairs
        unsigned dw0[8], dw1[8];
        cvtpk16(S0, dw0);
        cvtpk16(S1, dw1);
        // ---- PV tile 0 ----
#pragma unroll
        for (int kcl = 0; kcl < 2; kcl++) {
            unsigned a0 = dw0[(2 * kcl) * 2 + 0], b0 = dw0[(2 * kcl + 1) * 2 + 0];
            unsigned a1 = dw0[(2 * kcl) * 2 + 1], b1 = dw0[(2 * kcl + 1) * 2 + 1];
            plswap(a0, b0);
            plswap(a1, b1);
            u32x4 pw = {a0, a1, b0, b1};
            bf16x8 pb = __builtin_bit_cast(bf16x8, pw);
            int vcol = (kcl * 16 + hi * 8) ^ sw8;
            bf16x8 vf0 = *(const bf16x8*)&Vs[cur][l31][vcol];
            bf16x8 vf1 = *(const bf16x8*)&Vs[cur][32 + l31][vcol];
            __builtin_amdgcn_s_setprio(1);
            O0 = mfma32(vf0, pb, O0);
            O1 = mfma32(vf1, pb, O1);
            __builtin_amdgcn_s_setprio(0);
        }
        // ---- PV tile 1 ----
#pragma unroll
        for (int kcl = 0; kcl < 2; kcl++) {
            unsigned a0 = dw1[(2 * kcl) * 2 + 0], b0 = dw1[(2 * kcl + 1) * 2 + 0];
            unsigned a1 = dw1[(2 * kcl) * 2 + 1], b1 = dw1[(2 * kcl + 1) * 2 + 1];
            plswap(a0, b0);
            plswap(a1, b1);
            u32x4 pw = {a0, a1, b0, b1};
            bf16x8 pb = __builtin_bit_cast(bf16x8, pw);
            int vcol = ((2 + kcl) * 16 + hi * 8) ^ sw8;
            bf16x8 vf0 = *(const bf16x8*)&Vs[cur][l31][vcol];
            bf16x8 vf1 = *(const bf16x8*)&Vs[cur][32 + l31][vcol];
            __builtin_amdgcn_s_setprio(1);
            O0 = mfma32(vf0, pb, O0);
            O1 = mfma32(vf1, pb, O1);
            __builtin_amdgcn_s_setprio(0);
        }
        if (i < 15) __syncthreads();        // drains GLDS16 (vmcnt) + LDS reuse
    }

    float inv = 1.0f / l_run;
    size_t ob = ((size_t)(b * LQ) + qrow) * DQ + h * HD;
#pragma unroll
    for (int td = 0; td < 2; td++) {
        const f32x16& O = td ? O1 : O0;
#pragma unroll
        for (int g = 0; g < 4; g++) {
            bf16x4 ov = {(bf16)(O[4 * g + 0] * inv), (bf16)(O[4 * g + 1] * inv),
                         (bf16)(O[4 * g + 2] * inv), (bf16)(O[4 * g + 3] * inv)};
            *(bf16x4*)&o[ob + td * 32 + g * 8 + hi * 4] = ov;
        }
    }
}

// ---------------------------------------------------------------------------
extern "C" void kernel_launch(void* const* d_in, const int* in_sizes, int n_in,
                              void* d_out, int out_size, void* d_ws, size_t ws_size,
                              hipStream_t stream) {
    const float* x     = (const float*)d_in[0];
    const float* y     = (const float*)d_in[1];
    const float* x_cos = (const float*)d_in[2];
    const float* x_sin = (const float*)d_in[3];
    const float* y_cos = (const float*)d_in[4];
    const float* y_sin = (const float*)d_in[5];
    const float* Wq    = (const float*)d_in[6];
    const float* bq    = (const float*)d_in[7];
    const float* Wk    = (const float*)d_in[8];
    const float* bk    = (const float*)d_in[9];
    const float* Wv    = (const float*)d_in[10];
    const float* bv    = (const float*)d_in[11];
    const float* Wo    = (const float*)d_in[12];
    const float* bo    = (const float*)d_in[13];
    const float* gq    = (const float*)d_in[14];
    const float* gk    = (const float*)d_in[15];

    char* ws = (char*)d_ws;
    bf16* Wq_t = (bf16*)ws;  ws += (size_t)DQ * DQ * 2;
    bf16* Wk_t = (bf16*)ws;  ws += (size_t)DQ * DKV * 2;
    bf16* Wv_t = (bf16*)ws;  ws += (size_t)DQ * DKV * 2;
    bf16* Wo_t = (bf16*)ws;  ws += (size_t)DQ * DQ * 2;
    bf16* qbuf = (bf16*)ws;  ws += (size_t)NB * LQ * DQ * 2;
    bf16* kbuf = (bf16*)ws;  ws += (size_t)NB * LKV * DQ * 2;
    bf16* vT   = (bf16*)ws;  ws += (size_t)NB * NH * HD * LKV * 2;
    bf16* aout = (bf16*)ws;  ws += (size_t)NB * LQ * DQ * 2;
    bf16* yb   = (bf16*)ws;  ws += (size_t)NB * LKV * DKV * 2;
    bf16* xb   = aout;  // alias: xb dead (last read = Q-proj) before attn writes aout

    int nx8 = NB * LQ * DQ / 8, ny8 = NB * LKV * DKV / 8;
    prep<<<dim3(32, 32, 5), dim3(32, 8), 0, stream>>>(
        Wq, Wk, Wv, Wo, Wq_t, Wk_t, Wv_t, Wo_t,
        x, y, xb, yb, nx8, nx8 + ny8);

    gemm_qkv<<<dim3(8, 96), 256, 0, stream>>>(
        xb, Wq_t, bq, qbuf, yb, Wk_t, bk, kbuf, Wv_t, bv, vT);

    rmsnorm_rope3<<<NB * (LQ + LKV) / 4, 256, 0, stream>>>(
        qbuf, kbuf, gq, gk, x_cos, x_sin, y_cos, y_sin);

    attn_kern<<<dim3(LQ / 128, NH, NB), 256, 0, stream>>>(qbuf, kbuf, vT, aout);

    gemm_o<<<dim3(DQ / 128, NB * LQ / 128), 256, 0, stream>>>(aout, Wo_t, bo, d_out);
}

// Round 7
// 241.443 us; speedup vs baseline: 1.2397x; 1.0202x over previous
//
#include <hip/hip_runtime.h>

typedef __bf16 bf16;
typedef __bf16 bf16x4 __attribute__((ext_vector_type(4)));
typedef __bf16 bf16x8 __attribute__((ext_vector_type(8)));
typedef float  f32x4  __attribute__((ext_vector_type(4)));
typedef float  f32x16 __attribute__((ext_vector_type(16)));
typedef unsigned u32x4 __attribute__((ext_vector_type(4)));

#define NH   16
#define HD   64
#define DQ   1024
#define DKV  768
#define LQ   4096
#define LKV  1024
#define NB   2

__device__ __forceinline__ f32x4 mfma16(bf16x8 a, bf16x8 b, f32x4 c) {
    return __builtin_amdgcn_mfma_f32_16x16x32_bf16(a, b, c, 0, 0, 0);
}
__device__ __forceinline__ f32x16 mfma32(bf16x8 a, bf16x8 b, f32x16 c) {
    return __builtin_amdgcn_mfma_f32_32x32x16_bf16(a, b, c, 0, 0, 0);
}

// exchange a.hi-lanes <-> b.lo-lanes: after call a = (a.lo, b.lo), b = (a.hi, b.hi)
__device__ __forceinline__ void plswap(unsigned &a, unsigned &b) {
#if __has_builtin(__builtin_amdgcn_permlane32_swap)
    auto r = __builtin_amdgcn_permlane32_swap(a, b, false, false);
    a = (unsigned)r[0]; b = (unsigned)r[1];
#else
    asm volatile("v_permlane32_swap_b32 %0, %1" : "+v"(a), "+v"(b));
#endif
}

// cross-half (lane i <-> i+32) reduce via permlane32_swap — pure VALU, no DS op
__device__ __forceinline__ float xhalf_max(float v) {
    unsigned t = __builtin_bit_cast(unsigned, v), u = t;
    plswap(t, u);
    return fmaxf(__builtin_bit_cast(float, t), __builtin_bit_cast(float, u));
}
__device__ __forceinline__ float xhalf_add(float v) {
    unsigned t = __builtin_bit_cast(unsigned, v), u = t;
    plswap(t, u);
    return __builtin_bit_cast(float, t) + __builtin_bit_cast(float, u);
}

// T17: nested triples fuse to v_max3_f32 — 32-value max in ~17 ops (vs 31)
#define F3(a, b, c) fmaxf(fmaxf((a), (b)), (c))
__device__ __forceinline__ float vmax32(const f32x16& A, const f32x16& B) {
    float t0 = F3(A[0],  A[1],  A[2]);
    float t1 = F3(A[3],  A[4],  A[5]);
    float t2 = F3(A[6],  A[7],  A[8]);
    float t3 = F3(A[9],  A[10], A[11]);
    float t4 = F3(A[12], A[13], A[14]);
    float t5 = F3(A[15], B[0],  B[1]);
    float t6 = F3(B[2],  B[3],  B[4]);
    float t7 = F3(B[5],  B[6],  B[7]);
    float t8 = F3(B[8],  B[9],  B[10]);
    float t9 = F3(B[11], B[12], B[13]);
    float ta = fmaxf(B[14], B[15]);
    float u0 = F3(t0, t1, t2);
    float u1 = F3(t3, t4, t5);
    float u2 = F3(t6, t7, t8);
    float u3 = fmaxf(t9, ta);
    return fmaxf(F3(u0, u1, u2), u3);
}
__device__ __forceinline__ float vsum16(const f32x16& S) {
    float a = (S[0]  + S[1])  + (S[2]  + S[3]);
    float b = (S[4]  + S[5])  + (S[6]  + S[7]);
    float c = (S[8]  + S[9])  + (S[10] + S[11]);
    float d = (S[12] + S[13]) + (S[14] + S[15]);
    return (a + b) + (c + d);
}

__device__ __forceinline__ void cvtpk16(const f32x16& S, unsigned dw[8]) {
#pragma unroll
    for (int g = 0; g < 4; g++)
#pragma unroll
        for (int hh = 0; hh < 2; hh++) {
            unsigned d_;
            asm("v_cvt_pk_bf16_f32 %0, %1, %2"
                : "=v"(d_) : "v"(S[4 * g + 2 * hh]), "v"(S[4 * g + 2 * hh + 1]));
            dw[g * 2 + hh] = d_;
        }
}

// async global->LDS, 16B per lane; LDS dest wave-uniform base (HW adds lane*16)
#define GLDS16(g, l) __builtin_amdgcn_global_load_lds(                      \
    (const __attribute__((address_space(1))) void*)(g),                     \
    (__attribute__((address_space(3))) void*)(l), 16, 0, 0)

// ------- prep: 4 weight transposes (f32 KxN -> bf16 NxK) + x/y f32->bf16 -----
__global__ __launch_bounds__(256) void prep(
        const float* __restrict__ Wq, const float* __restrict__ Wk,
        const float* __restrict__ Wv, const float* __restrict__ Wo,
        bf16* __restrict__ Wq_t, bf16* __restrict__ Wk_t,
        bf16* __restrict__ Wv_t, bf16* __restrict__ Wo_t,
        const float* __restrict__ x, const float* __restrict__ y,
        bf16* __restrict__ xb, bf16* __restrict__ yb,
        int nx8, int ntot8) {
    if (blockIdx.z < 4) {
        __shared__ float tile[32][33];
        const float* in; bf16* out; int K;
        switch (blockIdx.z) {
            case 0:  in = Wq; out = Wq_t; K = DQ;  break;
            case 1:  in = Wk; out = Wk_t; K = DKV; break;
            case 2:  in = Wv; out = Wv_t; K = DKV; break;
            default: in = Wo; out = Wo_t; K = DQ;  break;
        }
        int n0 = blockIdx.x * 32, k0 = blockIdx.y * 32;
        if (k0 >= K) return;
        int tx = threadIdx.x, ty = threadIdx.y;  // (32,8)
        for (int yy = 0; yy < 32; yy += 8)
            tile[ty + yy][tx] = in[(size_t)(k0 + ty + yy) * DQ + n0 + tx];
        __syncthreads();
        for (int yy = 0; yy < 32; yy += 8)
            out[(size_t)(n0 + ty + yy) * K + k0 + tx] = (bf16)tile[tx][ty + yy];
    } else {
        int tid = threadIdx.y * 32 + threadIdx.x;
        int flat = (blockIdx.y * 32 + blockIdx.x) * 256 + tid;  // 0..262143
        for (int i = flat; i < ntot8; i += 32 * 32 * 256) {
            const float* in; bf16* out; int j;
            if (i < nx8) { in = x; out = xb; j = i; }
            else         { in = y; out = yb; j = i - nx8; }
            float4 a0 = ((const float4*)in)[(size_t)j * 2];
            float4 a1 = ((const float4*)in)[(size_t)j * 2 + 1];
            bf16x8 v = {(bf16)a0.x, (bf16)a0.y, (bf16)a0.z, (bf16)a0.w,
                        (bf16)a1.x, (bf16)a1.y, (bf16)a1.z, (bf16)a1.w};
            ((bf16x8*)out)[j] = v;
        }
    }
}

// ------- 128x128-tile GEMM body: C = A(MxK,bf16) @ Bt(NxK,bf16)^T + bias -----
// Minimum 2-phase pipeline (guide T3 recipe, no inline asm): double-buffered
// LDS; STAGE(next) issued BEFORE computing current so the in-flight loads hide
// under the MFMA phase; one __syncthreads per iteration AFTER compute.
// LDS tiles use a 16B-slot XOR swizzle (slot p of row r holds logical p^(r&3)):
// staging source pre-swizzled (GLDS dest stays linear, rule #21), fragment
// reads apply the same XOR -> 8-way bank conflict drops to 4-way.
// MODE 0: C bf16 row-major. MODE 1: V-transposed bf16 vT[b,h,d,kv]. MODE 2: C f32.
template <int MODE>
__device__ __forceinline__ void gemm_body(bf16* __restrict__ sm,
                                          const bf16* __restrict__ A,
                                          const bf16* __restrict__ Bt,
                                          const float* __restrict__ bias,
                                          void* __restrict__ Cv,
                                          int N, int K, int m0, int n0) {
    bf16* As = sm;              // [2][128*32]
    bf16* Bs = sm + 2 * 4096;   // [2][128*32]
    int tid  = threadIdx.x;
    int lane = tid & 63, w = tid >> 6;
    int quad = lane >> 4, l15 = lane & 15;
    int wm = (w >> 1) * 64, wn = (w & 1) * 64;
    int srow = tid >> 2;
    int scol = ((tid & 3) ^ (srow & 3)) * 8;     // pre-swizzled global source slot
    const bf16* Ag = &A [(size_t)(m0 + srow) * K + scol];
    const bf16* Bg = &Bt[(size_t)(n0 + srow) * K + scol];
    int woff = w * 512;
    int fcol = ((quad ^ (l15 & 3)) * 8);         // swizzled read slot (row&3==l15&3)

    f32x4 acc[4][4] = {};
    int nit = K >> 5;

#define STAGE(buf, kk) do {                                              \
        int k0_ = (kk) << 5;                                             \
        bf16* a_ = As + (buf) * 4096 + woff;                             \
        bf16* b_ = Bs + (buf) * 4096 + woff;                             \
        GLDS16(Ag + k0_,                  a_);                           \
        GLDS16(Ag + (size_t)64 * K + k0_, a_ + 2048);                    \
        GLDS16(Bg + k0_,                  b_);                           \
        GLDS16(Bg + (size_t)64 * K + k0_, b_ + 2048);                    \
    } while (0)

    STAGE(0, 0);
    __syncthreads();                  // implicit vmcnt(0): tile 0 landed

    for (int t = 0; t < nit; t++) {
        int cur = t & 1;
        if (t + 1 < nit) STAGE(cur ^ 1, t + 1);   // issue next-tile loads FIRST
        const bf16* Ac = As + cur * 4096;
        const bf16* Bc = Bs + cur * 4096;
        bf16x8 af[4], bfr[4];
#pragma unroll
        for (int i = 0; i < 4; i++)
            af[i] = *(const bf16x8*)&Ac[(wm + i * 16 + l15) * 32 + fcol];
#pragma unroll
        for (int j = 0; j < 4; j++)
            bfr[j] = *(const bf16x8*)&Bc[(wn + j * 16 + l15) * 32 + fcol];
#pragma unroll
        for (int i = 0; i < 4; i++)
#pragma unroll
            for (int j = 0; j < 4; j++)
                acc[i][j] = mfma16(af[i], bfr[j], acc[i][j]);
        __syncthreads();              // drains next-tile loads + guards reuse
    }
#undef STAGE

    bf16*  Cb = (bf16*)Cv;
    float* Cf = (float*)Cv;
#pragma unroll
    for (int i = 0; i < 4; i++)
#pragma unroll
        for (int j = 0; j < 4; j++) {
            int col = n0 + wn + j * 16 + l15;
            float bcol = bias[col];
            if (MODE == 1) {
                int rowb = m0 + wm + i * 16 + quad * 4;      // 4 consecutive kv
                int bb = rowb >> 10, kv = rowb & 1023;       // LKV = 1024
                int h = col >> 6, d = col & 63;
                bf16x4 val = {(bf16)(acc[i][j][0] + bcol), (bf16)(acc[i][j][1] + bcol),
                              (bf16)(acc[i][j][2] + bcol), (bf16)(acc[i][j][3] + bcol)};
                *(bf16x4*)&Cb[(((size_t)(bb * NH + h) * HD) + d) * LKV + kv] = val;
            } else {
#pragma unroll
                for (int r = 0; r < 4; r++) {
                    int row = m0 + wm + i * 16 + quad * 4 + r;
                    float v = acc[i][j][r] + bcol;
                    if (MODE == 2) Cf[(size_t)row * N + col] = v;
                    else           Cb[(size_t)row * N + col] = (bf16)v;
                }
            }
        }
}

// one launch, XCD-swizzled work map: yt<64 -> Q-proj, 64..79 -> K, 80..95 -> V
__global__ __launch_bounds__(256, 3) void gemm_qkv(
        const bf16* xb, const bf16* Wq_t, const float* bq, bf16* qbuf,
        const bf16* yb, const bf16* Wk_t, const float* bk, bf16* kbuf,
        const bf16* Wv_t, const float* bv, bf16* vT) {
    __shared__ bf16 sm[4 * 4096];
    int lin  = blockIdx.y * 8 + blockIdx.x;        // dispatch index, 768 blocks
    int work = (lin & 7) * 96 + (lin >> 3);        // bijective (768 % 8 == 0)
    int xt = work & 7, yt = work >> 3;
    if (yt < 64)      gemm_body<0>(sm, xb, Wq_t, bq, qbuf, DQ, DQ,  yt * 128,        xt * 128);
    else if (yt < 80) gemm_body<0>(sm, yb, Wk_t, bk, kbuf, DQ, DKV, (yt - 64) * 128, xt * 128);
    else              gemm_body<1>(sm, yb, Wv_t, bv, vT,   DQ, DKV, (yt - 80) * 128, xt * 128);
}
__global__ __launch_bounds__(256, 3) void gemm_o(const bf16* A, const bf16* Bt,
                                                 const float* bias, void* Cv) {
    __shared__ bf16 sm[4 * 4096];
    int lin  = blockIdx.y * 8 + blockIdx.x;        // 512 blocks
    int work = (lin & 7) * 64 + (lin >> 3);
    int xt = work & 7, yt = work >> 3;
    gemm_body<2>(sm, A, Bt, bias, Cv, DQ, DQ, yt * 128, xt * 128);
}

// ------- RMSNorm + RoPE, one wave per row, register-resident -----------------
__global__ __launch_bounds__(256) void rmsnorm_rope3(bf16* __restrict__ qb,
                                                     bf16* __restrict__ kb,
                                                     const float* __restrict__ gq,
                                                     const float* __restrict__ gk,
                                                     const float* __restrict__ xc,
                                                     const float* __restrict__ xs,
                                                     const float* __restrict__ yc,
                                                     const float* __restrict__ ys) {
    int w = threadIdx.x >> 6, lane = threadIdx.x & 63;
    int row = blockIdx.x * 4 + w;
    bf16* t; const float *g, *cs, *sn;
    if (row < NB * LQ) {
        t = qb + (size_t)row * DQ; g = gq;
        cs = xc + (size_t)row * HD; sn = xs + (size_t)row * HD;
    } else {
        int r2 = row - NB * LQ;
        t = kb + (size_t)r2 * DQ; g = gk;
        cs = yc + (size_t)r2 * HD; sn = ys + (size_t)r2 * HD;
    }
    int c0 = lane * 16;
    bf16x8 a0 = *(const bf16x8*)&t[c0];
    bf16x8 a1 = *(const bf16x8*)&t[c0 + 8];
    float vv[16], ss = 0.f;
#pragma unroll
    for (int j = 0; j < 8; j++) { vv[j] = (float)a0[j]; vv[8 + j] = (float)a1[j]; }
#pragma unroll
    for (int j = 0; j < 16; j++) ss += vv[j] * vv[j];
#pragma unroll
    for (int off = 32; off >= 1; off >>= 1) ss += __shfl_xor(ss, off, 64);
    float rms = rsqrtf(ss * (1.0f / 1024.0f) + 1e-6f);
    float nv[16];
#pragma unroll
    for (int j = 0; j < 16; j++) nv[j] = vv[j] * rms * g[c0 + j];
    int d0 = (lane & 3) * 16;
    float sgn = (lane & 2) ? 1.f : -1.f;   // d<32 -> -partner, d>=32 -> +partner
    bf16x8 o0, o1;
#pragma unroll
    for (int j = 0; j < 16; j++) {
        float pv = __shfl_xor(nv[j], 2, 64);
        float r = nv[j] * cs[d0 + j] + sgn * pv * sn[d0 + j];
        if (j < 8) o0[j] = (bf16)r; else o1[j - 8] = (bf16)r;
    }
    *(bf16x8*)&t[c0]     = o0;
    *(bf16x8*)&t[c0 + 8] = o1;
}

// ------- flash attention v9: 32x32 MFMA, in-register P, VALU-diet softmax ----
// block = (b,h,128 q rows); wave w owns q rows w*32..w*32+31 (q = l31, both
// hi-halves of the wave hold the same q, disjoint kv/d quarters).
// K/V chunk (64 kv) double-buffered in UNPADDED [64][64] LDS staged by
// global_load_lds with XOR-swizzled per-lane SOURCE addresses (rule #21).
// P never touches LDS (T12: v_cvt_pk_bf16_f32 + permlane32_swap).
// v9 (all exact-semantics): T17 max3 trees; fast-path vote on per-HALF max
// (identical vote outcome — __all spans both half-lanes of each q; the
// permlane cross-half merge moves to the rare slow path); one setprio pair
// per MFMA cluster; cvtpk(S1) placed after PV(t0) for MFMA/VALU overlap.
__global__ __launch_bounds__(256, 4) void attn_kern(const bf16* __restrict__ q,
                                                    const bf16* __restrict__ k,
                                                    const bf16* __restrict__ vT,
                                                    bf16* __restrict__ o) {
    __shared__ bf16 Ks[2][64][64];          // [buf][kv][d]   (swizzled slots)
    __shared__ bf16 Vs[2][64][64];          // [buf][d][kv]   (swizzled slots)
    int tid = threadIdx.x, w = tid >> 6, lane = tid & 63;
    int l31 = lane & 31, hi = lane >> 5;
    // XCD swizzle over 1024 blocks: same-(b,h) blocks share 256KB K/V in L2
    int lin  = blockIdx.x + (blockIdx.y << 5) + (blockIdx.z << 9);
    int work = (lin & 7) * 128 + (lin >> 3);
    int qt = work & 31, h = (work >> 5) & 15, b = work >> 9;
    int qrow = qt * 128 + w * 32 + l31;
    int sw8 = (l31 & 7) << 3;               // read-side element XOR (16B granular)

    // Q fragments (B-operand): col=q=l31, k(d) = kc*16 + hi*8 + e; fold 1/8 scale
    bf16x8 qf[4];
    {
        const bf16* qg = &q[((size_t)(b * LQ) + qrow) * DQ + h * HD + hi * 8];
#pragma unroll
        for (int kc = 0; kc < 4; kc++) {
            bf16x8 tq = *(const bf16x8*)(qg + kc * 16);
#pragma unroll
            for (int e = 0; e < 8; e++) tq[e] = (bf16)((float)tq[e] * 0.125f);
            qf[kc] = tq;
        }
    }

    // staging: wave w stages rows [w*16, w*16+16) of K (kv rows) and V (d rows).
    // each GLDS16 covers 8 rows: lane -> row rb+(lane>>3), dest slot lane&7;
    // source slot = (lane&7) ^ (row&7)  (inverse swizzle; (row+8)&7 == row&7)
    int rb = w * 16;
    int srow = rb + (lane >> 3);
    int sl = (lane & 7) ^ (srow & 7);
    const bf16* kg0 = &k[((size_t)(b * LKV) + srow) * DQ + h * HD + sl * 8];
    const bf16* vg0 = &vT[(((size_t)(b * NH + h) * HD) + srow) * LKV + sl * 8];

    GLDS16(kg0,                   &Ks[0][rb][0]);
    GLDS16(kg0 + (size_t)8 * DQ,  &Ks[0][rb + 8][0]);
    GLDS16(vg0,                   &Vs[0][rb][0]);
    GLDS16(vg0 + (size_t)8 * LKV, &Vs[0][rb + 8][0]);
    __syncthreads();

    f32x16 O0 = {}, O1 = {};
    float m_run = -1e30f, l_run = 0.f;

    for (int i = 0; i < 16; i++) {
        int cur = i & 1;
        if (i < 15) {                        // async prefetch of chunk i+1
            int nxt = cur ^ 1;
            size_t ko = (size_t)(i + 1) * 64 * DQ;
            int    vo = (i + 1) * 64;
            GLDS16(kg0 + ko,                   &Ks[nxt][rb][0]);
            GLDS16(kg0 + ko + (size_t)8 * DQ,  &Ks[nxt][rb + 8][0]);
            GLDS16(vg0 + vo,                   &Vs[nxt][rb][0]);
            GLDS16(vg0 + vo + (size_t)8 * LKV, &Vs[nxt][rb + 8][0]);
        }
        // ---- S for both 32-kv tiles, MFMAs back-to-back ----
        f32x16 S0 = {}, S1 = {};
        __builtin_amdgcn_s_setprio(1);
#pragma unroll
        for (int kc = 0; kc < 4; kc++) {
            bf16x8 kf0 = *(const bf16x8*)&Ks[cur][l31][(kc * 16 + hi * 8) ^ sw8];
            bf16x8 kf1 = *(const bf16x8*)&Ks[cur][32 + l31][(kc * 16 + hi * 8) ^ sw8];
            S0 = mfma32(kf0, qf[kc], S0);
            S1 = mfma32(kf1, qf[kc], S1);
        }
        __builtin_amdgcn_s_setprio(0);
        // ---- single online-softmax over the 64-kv chunk (T13 defer-max) ----
        // vote on per-half max: __all covers both (q,hi) lanes => same outcome
        float pmax = vmax32(S0, S1);
        if (!__all(pmax - m_run <= 8.f)) {   // rare slow path
            float pm2 = xhalf_max(pmax);
            float mn = fmaxf(m_run, pm2);
            float alpha = __expf(m_run - mn);
            m_run = mn; l_run *= alpha;
#pragma unroll
            for (int r = 0; r < 16; r++) { O0[r] *= alpha; O1[r] *= alpha; }
        }
#pragma unroll
        for (int r = 0; r < 16; r++) S0[r] = __expf(S0[r] - m_run);
#pragma unroll
        for (int r = 0; r < 16; r++) S1[r] = __expf(S1[r] - m_run);
        float rs = vsum16(S0) + vsum16(S1);
        l_run += xhalf_add(rs);
        // pack P(t0) now; P(t1) packs after PV(t0) so it overlaps the MFMAs
        unsigned dw0[8], dw1[8];
        cvtpk16(S0, dw0);
        // ---- PV tile 0 ----
        {
            unsigned a0 = dw0[0], b0 = dw0[2], a1 = dw0[1], b1 = dw0[3];
            unsigned c0 = dw0[4], e0 = dw0[6], c1 = dw0[5], e1 = dw0[7];
            plswap(a0, b0); plswap(a1, b1);
            plswap(c0, e0); plswap(c1, e1);
            u32x4 pw0 = {a0, a1, b0, b1};
            u32x4 pw1 = {c0, c1, e0, e1};
            bf16x8 pba = __builtin_bit_cast(bf16x8, pw0);
            bf16x8 pbb = __builtin_bit_cast(bf16x8, pw1);
            int vc0 = (hi * 8) ^ sw8;
            int vc1 = (16 + hi * 8) ^ sw8;
            bf16x8 vfa0 = *(const bf16x8*)&Vs[cur][l31][vc0];
            bf16x8 vfa1 = *(const bf16x8*)&Vs[cur][32 + l31][vc0];
            bf16x8 vfb0 = *(const bf16x8*)&Vs[cur][l31][vc1];
            bf16x8 vfb1 = *(const bf16x8*)&Vs[cur][32 + l31][vc1];
            __builtin_amdgcn_s_setprio(1);
            O0 = mfma32(vfa0, pba, O0);
            O1 = mfma32(vfa1, pba, O1);
            O0 = mfma32(vfb0, pbb, O0);
            O1 = mfma32(vfb1, pbb, O1);
            __builtin_amdgcn_s_setprio(0);
        }
        // ---- pack P(t1) (overlaps PV(t0) drain), then PV tile 1 ----
        cvtpk16(S1, dw1);
        {
            unsigned a0 = dw1[0], b0 = dw1[2], a1 = dw1[1], b1 = dw1[3];
            unsigned c0 = dw1[4], e0 = dw1[6], c1 = dw1[5], e1 = dw1[7];
            plswap(a0, b0); plswap(a1, b1);
            plswap(c0, e0); plswap(c1, e1);
            u32x4 pw0 = {a0, a1, b0, b1};
            u32x4 pw1 = {c0, c1, e0, e1};
            bf16x8 pba = __builtin_bit_cast(bf16x8, pw0);
            bf16x8 pbb = __builtin_bit_cast(bf16x8, pw1);
            int vc0 = (32 + hi * 8) ^ sw8;
            int vc1 = (48 + hi * 8) ^ sw8;
            bf16x8 vfa0 = *(const bf16x8*)&Vs[cur][l31][vc0];
            bf16x8 vfa1 = *(const bf16x8*)&Vs[cur][32 + l31][vc0];
            bf16x8 vfb0 = *(const bf16x8*)&Vs[cur][l31][vc1];
            bf16x8 vfb1 = *(const bf16x8*)&Vs[cur][32 + l31][vc1];
            __builtin_amdgcn_s_setprio(1);
            O0 = mfma32(vfa0, pba, O0);
            O1 = mfma32(vfa1, pba, O1);
            O0 = mfma32(vfb0, pbb, O0);
            O1 = mfma32(vfb1, pbb, O1);
            __builtin_amdgcn_s_setprio(0);
        }
        if (i < 15) __syncthreads();        // drains GLDS16 (vmcnt) + LDS reuse
    }

    float inv = 1.0f / l_run;
    size_t ob = ((size_t)(b * LQ) + qrow) * DQ + h * HD;
#pragma unroll
    for (int td = 0; td < 2; td++) {
        const f32x16& O = td ? O1 : O0;
#pragma unroll
        for (int g = 0; g < 4; g++) {
            bf16x4 ov = {(bf16)(O[4 * g + 0] * inv), (bf16)(O[4 * g + 1] * inv),
                         (bf16)(O[4 * g + 2] * inv), (bf16)(O[4 * g + 3] * inv)};
            *(bf16x4*)&o[ob + td * 32 + g * 8 + hi * 4] = ov;
        }
    }
}

// ---------------------------------------------------------------------------
extern "C" void kernel_launch(void* const* d_in, const int* in_sizes, int n_in,
                              void* d_out, int out_size, void* d_ws, size_t ws_size,
                              hipStream_t stream) {
    const float* x     = (const float*)d_in[0];
    const float* y     = (const float*)d_in[1];
    const float* x_cos = (const float*)d_in[2];
    const float* x_sin = (const float*)d_in[3];
    const float* y_cos = (const float*)d_in[4];
    const float* y_sin = (const float*)d_in[5];
    const float* Wq    = (const float*)d_in[6];
    const float* bq    = (const float*)d_in[7];
    const float* Wk    = (const float*)d_in[8];
    const float* bk    = (const float*)d_in[9];
    const float* Wv    = (const float*)d_in[10];
    const float* bv    = (const float*)d_in[11];
    const float* Wo    = (const float*)d_in[12];
    const float* bo    = (const float*)d_in[13];
    const float* gq    = (const float*)d_in[14];
    const float* gk    = (const float*)d_in[15];

    char* ws = (char*)d_ws;
    bf16* Wq_t = (bf16*)ws;  ws += (size_t)DQ * DQ * 2;
    bf16* Wk_t = (bf16*)ws;  ws += (size_t)DQ * DKV * 2;
    bf16* Wv_t = (bf16*)ws;  ws += (size_t)DQ * DKV * 2;
    bf16* Wo_t = (bf16*)ws;  ws += (size_t)DQ * DQ * 2;
    bf16* qbuf = (bf16*)ws;  ws += (size_t)NB * LQ * DQ * 2;
    bf16* kbuf = (bf16*)ws;  ws += (size_t)NB * LKV * DQ * 2;
    bf16* vT   = (bf16*)ws;  ws += (size_t)NB * NH * HD * LKV * 2;
    bf16* aout = (bf16*)ws;  ws += (size_t)NB * LQ * DQ * 2;
    bf16* yb   = (bf16*)ws;  ws += (size_t)NB * LKV * DKV * 2;
    bf16* xb   = aout;  // alias: xb dead (last read = Q-proj) before attn writes aout

    int nx8 = NB * LQ * DQ / 8, ny8 = NB * LKV * DKV / 8;
    prep<<<dim3(32, 32, 5), dim3(32, 8), 0, stream>>>(
        Wq, Wk, Wv, Wo, Wq_t, Wk_t, Wv_t, Wo_t,
        x, y, xb, yb, nx8, nx8 + ny8);

    gemm_qkv<<<dim3(8, 96), 256, 0, stream>>>(
        xb, Wq_t, bq, qbuf, yb, Wk_t, bk, kbuf, Wv_t, bv, vT);

    rmsnorm_rope3<<<NB * (LQ + LKV) / 4, 256, 0, stream>>>(
        qbuf, kbuf, gq, gk, x_cos, x_sin, y_cos, y_sin);

    attn_kern<<<dim3(LQ / 128, NH, NB), 256, 0, stream>>>(qbuf, kbuf, vT, aout);

    gemm_o<<<dim3(DQ / 128, NB * LQ / 128), 256, 0, stream>>>(aout, Wo_t, bo, d_out);
}